// Round 1
// baseline (170.682 us; speedup 1.0000x reference)
//
#include <hip/hip_runtime.h>
#include <hip/hip_bf16.h>
#include <cstdint>

// ConViT GPSA fused pipeline, bf16 MFMA throughout (threshold is bf16-grade).
// ws layout (needs ~44.9 MB):
//   xb(7.08M) wqb/wkb/wvb/wpb(1.18M ea) Q(9.44M) K(9.44M) VT(7.08M) O(7.08M) posmax/posdinv(36K ea)

typedef unsigned short u16;
typedef __attribute__((ext_vector_type(8))) short bf16x8;
typedef __attribute__((ext_vector_type(4))) float f32x4;

__device__ __forceinline__ u16 f2bf(float f) {
  union { float f; uint32_t u; } v; v.f = f;
  uint32_t r = v.u + 0x7FFFu + ((v.u >> 16) & 1u);  // RNE (no NaN in this workload)
  return (u16)(r >> 16);
}

// ---------------- f32 -> bf16 converters ----------------
__global__ __launch_bounds__(256) void cvt_f32_bf16(const float* __restrict__ s,
                                                    u16* __restrict__ d, int n4) {
  int i = blockIdx.x * 256 + threadIdx.x;
  if (i >= n4) return;
  const float4 v = ((const float4*)s)[i];
  ushort4 o;
  o.x = f2bf(v.x); o.y = f2bf(v.y); o.z = f2bf(v.z); o.w = f2bf(v.w);
  ((ushort4*)d)[i] = o;
}

__global__ __launch_bounds__(256) void cvt_w4(const float* __restrict__ s0,
                                              const float* __restrict__ s1,
                                              const float* __restrict__ s2,
                                              const float* __restrict__ s3,
                                              u16* __restrict__ d) {
  const int which = blockIdx.y;
  const float* s = which == 0 ? s0 : which == 1 ? s1 : which == 2 ? s2 : s3;
  u16* dd = d + (size_t)which * 589824;
  const int i = blockIdx.x * 256 + threadIdx.x;  // exactly 576*256 = 147456 per weight
  const float4 v = ((const float4*)s)[i];
  ushort4 o;
  o.x = f2bf(v.x); o.y = f2bf(v.y); o.z = f2bf(v.z); o.w = f2bf(v.w);
  ((ushort4*)dd)[i] = o;
}

// ---------------- positional softmax row stats ----------------
// pos[h,n,m] = W0*dx + W1*dy + W2*(dx^2+dy^2) + bpos[h]; store rowmax and 1/sum(exp(p-max)).
__global__ __launch_bounds__(256) void pos_prep(const float* __restrict__ Wpos,
                                                const float* __restrict__ bpos,
                                                float* __restrict__ posmax,
                                                float* __restrict__ posdinv) {
  const int w = threadIdx.x >> 6, lane = threadIdx.x & 63;
  const int row = blockIdx.x * 4 + w;            // 0..9215  (h*576+n)
  const int h = row / 576, n = row - h * 576;
  const float w0 = Wpos[h * 3 + 0], w1 = Wpos[h * 3 + 1], w2 = Wpos[h * 3 + 2], bp = bpos[h];
  const int qr = n / 24, qc = n - qr * 24;
  float vals[9];
  float mx = -1e30f;
#pragma unroll
  for (int i = 0; i < 9; ++i) {
    const int m = i * 64 + lane;
    const int kr = m / 24, kc = m - kr * 24;
    const float dx = (float)(kc - qc), dy = (float)(kr - qr);
    const float p = w0 * dx + w1 * dy + w2 * (dx * dx + dy * dy) + bp;
    vals[i] = p;
    mx = fmaxf(mx, p);
  }
#pragma unroll
  for (int off = 1; off < 64; off <<= 1) mx = fmaxf(mx, __shfl_xor(mx, off, 64));
  float s = 0.f;
#pragma unroll
  for (int i = 0; i < 9; ++i) s += __expf(vals[i] - mx);
#pragma unroll
  for (int off = 1; off < 64; off <<= 1) s += __shfl_xor(s, off, 64);
  if (lane == 0) { posmax[row] = mx; posdinv[row] = 1.f / s; }
}

// ---------------- shared GEMM-BT core (C = A @ B^T), K = 768 ----------------
// A (M x 768) bf16 row-major, B (N x 768) bf16 row-major. 128x128 block tile,
// 4 waves in 2x2, each wave 64x64 = 4x4 16x16 frags, BK = 32 (one mfma K-step).
// MODE 0: Q/K proj (A=W, B=x; D is Y^T): write (bh, n, 64-padded) bf16, blockIdx.y picks Wq/Wk.
// MODE 1: V proj   (A=x, B=Wv; D is Y):  write V^T as (bh, d, 576) bf16.
// MODE 2: out proj (A=Wproj, B=O; D is Y^T): write f32 (bn,768) + bias.
template <int MODE>
__global__ __launch_bounds__(256) void gemm_bt(
    const u16* __restrict__ A0, const u16* __restrict__ A1, const u16* __restrict__ B,
    u16* __restrict__ ob0, u16* __restrict__ ob1,
    float* __restrict__ of, const float* __restrict__ bias, int NT) {
  __shared__ u16 sA[128][40];  // +8 u16 pad -> 80B row stride, conflict-light b128 reads
  __shared__ u16 sB[128][40];

  const u16* A = blockIdx.y == 0 ? A0 : A1;
  u16* ob = blockIdx.y == 0 ? ob0 : ob1;

  const int mt = blockIdx.x / NT, nt = blockIdx.x % NT;
  const int mbase = mt * 128, nbase = nt * 128;
  const int tid = threadIdx.x;
  const int w = tid >> 6, lane = tid & 63;
  const int wr = w >> 1, wc = w & 1;
  const int lg = lane >> 4, lc = lane & 15;

  const int rS = tid >> 2;         // staging row 0..63 (and +64)
  const int cS = (tid & 3) * 8;    // staging col (elements)

  const u16* gA0 = A + (size_t)(mbase + rS) * 768 + cS;
  const u16* gA1 = gA0 + (size_t)64 * 768;
  const u16* gB0 = B + (size_t)(nbase + rS) * 768 + cS;
  const u16* gB1 = gB0 + (size_t)64 * 768;

  const f32x4 vzero = {0.f, 0.f, 0.f, 0.f};
  f32x4 acc[4][4];
#pragma unroll
  for (int i = 0; i < 4; ++i)
#pragma unroll
    for (int j = 0; j < 4; ++j) acc[i][j] = vzero;

  for (int kt = 0; kt < 24; ++kt) {
    const int kb = kt * 32;
    const bf16x8 a0 = *(const bf16x8*)(gA0 + kb);
    const bf16x8 a1 = *(const bf16x8*)(gA1 + kb);
    const bf16x8 b0 = *(const bf16x8*)(gB0 + kb);
    const bf16x8 b1 = *(const bf16x8*)(gB1 + kb);
    __syncthreads();  // previous iter's frag reads done before overwrite
    *(bf16x8*)&sA[rS][cS] = a0;
    *(bf16x8*)&sA[rS + 64][cS] = a1;
    *(bf16x8*)&sB[rS][cS] = b0;
    *(bf16x8*)&sB[rS + 64][cS] = b1;
    __syncthreads();
    bf16x8 av[4], bv[4];
#pragma unroll
    for (int i = 0; i < 4; ++i) av[i] = *(const bf16x8*)&sA[wr * 64 + i * 16 + lc][lg * 8];
#pragma unroll
    for (int jn = 0; jn < 4; ++jn) bv[jn] = *(const bf16x8*)&sB[wc * 64 + jn * 16 + lc][lg * 8];
#pragma unroll
    for (int i = 0; i < 4; ++i)
#pragma unroll
      for (int jn = 0; jn < 4; ++jn)
        acc[i][jn] = __builtin_amdgcn_mfma_f32_16x16x32_bf16(av[i], bv[jn], acc[i][jn], 0, 0, 0);
  }

  // D layout: col(n-dim) = lc, row(m-dim) = lg*4 + reg  -> 4 consecutive m per lane.
  if constexpr (MODE == 0) {
#pragma unroll
    for (int i = 0; i < 4; ++i) {
      const int c0 = mbase + wr * 64 + i * 16 + lg * 4;  // channel, 4 consecutive (one head)
      const int hh = c0 / 48;
      const int d0 = c0 - hh * 48;
#pragma unroll
      for (int jn = 0; jn < 4; ++jn) {
        const int bn = nbase + wc * 64 + jn * 16 + lc;
        const int bb = bn / 576;
        const int nn = bn - bb * 576;
        ushort4 o;
        o.x = f2bf(acc[i][jn][0]); o.y = f2bf(acc[i][jn][1]);
        o.z = f2bf(acc[i][jn][2]); o.w = f2bf(acc[i][jn][3]);
        *(ushort4*)&ob[(((size_t)bb * 16 + hh) * 576 + nn) * 64 + d0] = o;
      }
    }
  } else if constexpr (MODE == 1) {
#pragma unroll
    for (int i = 0; i < 4; ++i) {
      const int bn0 = mbase + wr * 64 + i * 16 + lg * 4;  // 4 consecutive tokens (one b)
      const int bb = bn0 / 576;
      const int nn0 = bn0 - bb * 576;
#pragma unroll
      for (int jn = 0; jn < 4; ++jn) {
        const int c = nbase + wc * 64 + jn * 16 + lc;
        const int hh = c / 48;
        const int dd = c - hh * 48;
        ushort4 o;
        o.x = f2bf(acc[i][jn][0]); o.y = f2bf(acc[i][jn][1]);
        o.z = f2bf(acc[i][jn][2]); o.w = f2bf(acc[i][jn][3]);
        *(ushort4*)&ob[(((size_t)bb * 16 + hh) * 48 + dd) * 576 + nn0] = o;
      }
    }
  } else {
#pragma unroll
    for (int i = 0; i < 4; ++i) {
      const int c0 = mbase + wr * 64 + i * 16 + lg * 4;
      const float4 b4 = *(const float4*)&bias[c0];
#pragma unroll
      for (int jn = 0; jn < 4; ++jn) {
        const int bn = nbase + wc * 64 + jn * 16 + lc;
        float4 o;
        o.x = acc[i][jn][0] + b4.x; o.y = acc[i][jn][1] + b4.y;
        o.z = acc[i][jn][2] + b4.z; o.w = acc[i][jn][3] + b4.w;
        *(float4*)&of[(size_t)bn * 768 + c0] = o;
      }
    }
  }
}

// ---------------- fused gated attention ----------------
// Block = (qtile 64 rows) x (head) x (batch); 4 waves, wave = 16 q-rows.
// Scores bounded (|s*scale| < ~2) -> exp without max-subtraction; patch part
// accumulated unnormalized + row-sum l; pos part normalized on the fly via
// precomputed rowmax/denom. O = (1-g)*O_p/l + g*O_pos. (attn row-sum == 1 exactly.)
__global__ __launch_bounds__(256) void attn_fused(
    const u16* __restrict__ Q, const u16* __restrict__ K, const u16* __restrict__ VT,
    const float* __restrict__ posmax, const float* __restrict__ posdinv,
    const float* __restrict__ Wpos, const float* __restrict__ bpos,
    const float* __restrict__ gating, u16* __restrict__ O) {
  const int qt = blockIdx.x, h = blockIdx.y, b = blockIdx.z;
  const int tid = threadIdx.x;
  const int w = tid >> 6, lane = tid & 63;
  const int lg = lane >> 4, lc = lane & 15;
  const int bh = b * 16 + h;

  const u16* Qh = Q + (size_t)bh * 576 * 64;
  const u16* Kh = K + (size_t)bh * 576 * 64;
  const u16* Vh = VT + (size_t)bh * 48 * 576;

  __shared__ u16 pls[4][2][16][40];  // per-wave P repack: [wave][patch|pos][qrow][32 keys + pad]

  const int qbase = qt * 64 + w * 16;
  const bf16x8 aq0 = *(const bf16x8*)&Qh[(qbase + lc) * 64 + lg * 8];
  const bf16x8 aq1 = *(const bf16x8*)&Qh[(qbase + lc) * 64 + lg * 8 + 32];

  const float scale = 0.14433756729740643f;  // 48^-0.5
  const float g = 1.f / (1.f + __expf(-gating[h]));
  const float omg = 1.f - g;
  const float w0 = Wpos[h * 3 + 0], w1 = Wpos[h * 3 + 1], w2 = Wpos[h * 3 + 2], bp = bpos[h];

  const int qg0 = qbase + lg * 4;
  float pmax[4], pdinv[4], qrow[4], qcol[4];
#pragma unroll
  for (int j = 0; j < 4; ++j) {
    pmax[j] = posmax[h * 576 + qg0 + j];
    pdinv[j] = posdinv[h * 576 + qg0 + j];
    const int qi = qg0 + j;
    const int qr = qi / 24;
    qrow[j] = (float)qr;
    qcol[j] = (float)(qi - qr * 24);
  }

  const f32x4 vzero = {0.f, 0.f, 0.f, 0.f};
  f32x4 accP[3], accG[3];
#pragma unroll
  for (int dt = 0; dt < 3; ++dt) { accP[dt] = vzero; accG[dt] = vzero; }
  float lsum[4] = {0.f, 0.f, 0.f, 0.f};

  for (int kc = 0; kc < 18; ++kc) {
    const int k0 = kc * 32;
#pragma unroll
    for (int t = 0; t < 2; ++t) {
      const int ki = k0 + t * 16 + lc;  // key index (D col = lc)
      const bf16x8 kb0 = *(const bf16x8*)&Kh[ki * 64 + lg * 8];
      const bf16x8 kb1 = *(const bf16x8*)&Kh[ki * 64 + lg * 8 + 32];
      f32x4 s = vzero;
      s = __builtin_amdgcn_mfma_f32_16x16x32_bf16(aq0, kb0, s, 0, 0, 0);
      s = __builtin_amdgcn_mfma_f32_16x16x32_bf16(aq1, kb1, s, 0, 0, 0);
      const int kri = ki / 24;
      const float kcf = (float)(ki - kri * 24), krf = (float)kri;
#pragma unroll
      for (int j = 0; j < 4; ++j) {  // D row (q-row local) = lg*4 + j
        const float pp = __expf(s[j] * scale);
        lsum[j] += pp;
        const float dx = kcf - qcol[j];
        const float dy = krf - qrow[j];
        const float pv = w0 * dx + w1 * dy + w2 * (dx * dx + dy * dy) + bp;
        const float pg = __expf(pv - pmax[j]) * pdinv[j];
        pls[w][0][lg * 4 + j][t * 16 + lc] = f2bf(pp);
        pls[w][1][lg * 4 + j][t * 16 + lc] = f2bf(pg);
      }
    }
    asm volatile("s_waitcnt lgkmcnt(0)" ::: "memory");  // wave-private LDS write->read
    const bf16x8 pa = *(const bf16x8*)&pls[w][0][lc][lg * 8];
    const bf16x8 ga = *(const bf16x8*)&pls[w][1][lc][lg * 8];
    asm volatile("" ::: "memory");  // keep next-iter writes after these reads
#pragma unroll
    for (int dt = 0; dt < 3; ++dt) {
      const bf16x8 vb = *(const bf16x8*)&Vh[(dt * 16 + lc) * 576 + k0 + lg * 8];
      accP[dt] = __builtin_amdgcn_mfma_f32_16x16x32_bf16(pa, vb, accP[dt], 0, 0, 0);
      accG[dt] = __builtin_amdgcn_mfma_f32_16x16x32_bf16(ga, vb, accG[dt], 0, 0, 0);
    }
  }

  float linv[4];
#pragma unroll
  for (int j = 0; j < 4; ++j) {
    float sv = lsum[j];
    sv += __shfl_xor(sv, 1, 64);
    sv += __shfl_xor(sv, 2, 64);
    sv += __shfl_xor(sv, 4, 64);
    sv += __shfl_xor(sv, 8, 64);
    linv[j] = 1.f / sv;
  }
#pragma unroll
  for (int dt = 0; dt < 3; ++dt) {
#pragma unroll
    for (int j = 0; j < 4; ++j) {
      const float val = omg * accP[dt][j] * linv[j] + g * accG[dt][j];
      const int qg = qbase + lg * 4 + j;
      O[((size_t)(b * 576 + qg)) * 768 + h * 48 + dt * 16 + lc] = f2bf(val);
    }
  }
}

// ---------------- launch ----------------
extern "C" void kernel_launch(void* const* d_in, const int* in_sizes, int n_in,
                              void* d_out, int out_size, void* d_ws, size_t ws_size,
                              hipStream_t stream) {
  const float* x      = (const float*)d_in[0];
  const float* Wq     = (const float*)d_in[1];
  const float* Wk     = (const float*)d_in[2];
  const float* Wv     = (const float*)d_in[3];
  const float* Wp     = (const float*)d_in[4];
  const float* bproj  = (const float*)d_in[5];
  const float* Wpos   = (const float*)d_in[6];
  const float* bpos   = (const float*)d_in[7];
  const float* gating = (const float*)d_in[8];
  float* out = (float*)d_out;

  char* ws = (char*)d_ws;
  u16* xb      = (u16*)(ws + 0);
  u16* wqb     = (u16*)(ws + 7077888);
  u16* wkb     = (u16*)(ws + 8257536);
  u16* wvb     = (u16*)(ws + 9437184);
  u16* wpb     = (u16*)(ws + 10616832);
  u16* Qw      = (u16*)(ws + 11796480);
  u16* Kw      = (u16*)(ws + 21233664);
  u16* VTw     = (u16*)(ws + 30670848);
  u16* Ow      = (u16*)(ws + 37748736);
  float* pmax  = (float*)(ws + 44826624);
  float* pdinv = (float*)(ws + 44863488);

  cvt_f32_bf16<<<dim3(3456), dim3(256), 0, stream>>>(x, xb, 884736);
  cvt_w4<<<dim3(576, 4), dim3(256), 0, stream>>>(Wq, Wk, Wv, Wp, wqb);
  // zero Q+K (contiguous) so head-dim pad 48..63 is zero for the K=64 MFMA
  hipMemsetAsync(Qw, 0, 18874368, stream);
  gemm_bt<0><<<dim3(216, 2), dim3(256), 0, stream>>>(wqb, wkb, xb, Qw, Kw, nullptr, nullptr, 36);
  gemm_bt<1><<<dim3(216, 1), dim3(256), 0, stream>>>(xb, xb, wvb, VTw, VTw, nullptr, nullptr, 6);
  pos_prep<<<dim3(2304), dim3(256), 0, stream>>>(Wpos, bpos, pmax, pdinv);
  attn_fused<<<dim3(9, 16, 8), dim3(256), 0, stream>>>(Qw, Kw, VTw, pmax, pdinv, Wpos, bpos,
                                                       gating, Ow);
  gemm_bt<2><<<dim3(216, 1), dim3(256), 0, stream>>>(wpb, wpb, Ow, nullptr, nullptr, out, bproj, 36);
}

// Round 2
// 169.949 us; speedup vs baseline: 1.0043x; 1.0043x over previous
//
#include <hip/hip_runtime.h>
#include <hip/hip_bf16.h>
#include <cstdint>

// ConViT GPSA fused pipeline, bf16 MFMA throughout.
// ws layout (~44.9 MB): xb(7.08M) wqb/wkb/wvb/wpb(1.18M ea) Q(9.44M) K(9.44M)
// VT(7.08M) O(7.08M); posg(10.6M) overlays [xb..wvb] after the QKV GEMMs consume them.

typedef unsigned short u16;
typedef __attribute__((ext_vector_type(8))) short bf16x8;
typedef __attribute__((ext_vector_type(4))) float f32x4;

__device__ __forceinline__ u16 f2bf(float f) {
  union { float f; uint32_t u; } v; v.f = f;
  uint32_t r = v.u + 0x7FFFu + ((v.u >> 16) & 1u);  // RNE (no NaN in this workload)
  return (u16)(r >> 16);
}

// ---------------- f32 -> bf16 converters ----------------
__global__ __launch_bounds__(256) void cvt_f32_bf16(const float* __restrict__ s,
                                                    u16* __restrict__ d, int n4) {
  int i = blockIdx.x * 256 + threadIdx.x;
  if (i >= n4) return;
  const float4 v = ((const float4*)s)[i];
  ushort4 o;
  o.x = f2bf(v.x); o.y = f2bf(v.y); o.z = f2bf(v.z); o.w = f2bf(v.w);
  ((ushort4*)d)[i] = o;
}

__global__ __launch_bounds__(256) void cvt_w4(const float* __restrict__ s0,
                                              const float* __restrict__ s1,
                                              const float* __restrict__ s2,
                                              const float* __restrict__ s3,
                                              u16* __restrict__ d) {
  const int which = blockIdx.y;
  const float* s = which == 0 ? s0 : which == 1 ? s1 : which == 2 ? s2 : s3;
  u16* dd = d + (size_t)which * 589824;
  const int i = blockIdx.x * 256 + threadIdx.x;  // 576*256 = 147456 per weight
  const float4 v = ((const float4*)s)[i];
  ushort4 o;
  o.x = f2bf(v.x); o.y = f2bf(v.y); o.z = f2bf(v.z); o.w = f2bf(v.w);
  ((ushort4*)dd)[i] = o;
}

// ---------------- g-scaled positional softmax, materialized ----------------
// posg[h*576+n][m] = sigmoid(gating[h]) * softmax_m(W0*dx + W1*dy + W2*dd + bpos[h])
// Row-major in m -> directly loadable as PV A-fragments in attn (no repack).
__global__ __launch_bounds__(256) void pos_soft(const float* __restrict__ Wpos,
                                                const float* __restrict__ bpos,
                                                const float* __restrict__ gating,
                                                u16* __restrict__ posg) {
  const int w = threadIdx.x >> 6, lane = threadIdx.x & 63;
  const int row = blockIdx.x * 4 + w;            // 0..9215  (h*576+n)
  const int h = row / 576, n = row - h * 576;
  const float w0 = Wpos[h * 3 + 0], w1 = Wpos[h * 3 + 1], w2 = Wpos[h * 3 + 2], bp = bpos[h];
  const float g = 1.f / (1.f + __expf(-gating[h]));
  const int qr = n / 24, qc = n - qr * 24;
  float evals[9];
  float mx = -1e30f;
  float vals[9];
#pragma unroll
  for (int i = 0; i < 9; ++i) {
    const int m = i * 64 + lane;
    const int kr = m / 24, kc = m - kr * 24;
    const float dx = (float)(kc - qc), dy = (float)(kr - qr);
    const float p = w0 * dx + w1 * dy + w2 * (dx * dx + dy * dy) + bp;
    vals[i] = p;
    mx = fmaxf(mx, p);
  }
#pragma unroll
  for (int off = 1; off < 64; off <<= 1) mx = fmaxf(mx, __shfl_xor(mx, off, 64));
  float s = 0.f;
#pragma unroll
  for (int i = 0; i < 9; ++i) { evals[i] = __expf(vals[i] - mx); s += evals[i]; }
#pragma unroll
  for (int off = 1; off < 64; off <<= 1) s += __shfl_xor(s, off, 64);
  const float gi = g / s;
  u16* out = posg + (size_t)row * 576;
#pragma unroll
  for (int i = 0; i < 9; ++i) out[i * 64 + lane] = f2bf(evals[i] * gi);
}

// ---------------- shared GEMM-BT core (C = A @ B^T), K = 768 ----------------
// MODE 0: Q/K proj (A=W, B=x; D is Y^T): write (bh, n, 64-padded) bf16; y==0 (Q) pre-scaled.
// MODE 1: V proj   (A=x, B=Wv; D is Y):  write V^T as (bh, d, 576) bf16.
// MODE 2: out proj (A=Wproj, B=O; D is Y^T): write f32 (bn,768) + bias.
template <int MODE>
__global__ __launch_bounds__(256) void gemm_bt(
    const u16* __restrict__ A0, const u16* __restrict__ A1, const u16* __restrict__ B,
    u16* __restrict__ ob0, u16* __restrict__ ob1,
    float* __restrict__ of, const float* __restrict__ bias, int NT) {
  __shared__ u16 sA[128][40];  // +8 u16 pad
  __shared__ u16 sB[128][40];

  const u16* A = blockIdx.y == 0 ? A0 : A1;
  u16* ob = blockIdx.y == 0 ? ob0 : ob1;

  const int mt = blockIdx.x / NT, nt = blockIdx.x % NT;
  const int mbase = mt * 128, nbase = nt * 128;
  const int tid = threadIdx.x;
  const int w = tid >> 6, lane = tid & 63;
  const int wr = w >> 1, wc = w & 1;
  const int lg = lane >> 4, lc = lane & 15;

  const int rS = tid >> 2;
  const int cS = (tid & 3) * 8;

  const u16* gA0 = A + (size_t)(mbase + rS) * 768 + cS;
  const u16* gA1 = gA0 + (size_t)64 * 768;
  const u16* gB0 = B + (size_t)(nbase + rS) * 768 + cS;
  const u16* gB1 = gB0 + (size_t)64 * 768;

  const f32x4 vzero = {0.f, 0.f, 0.f, 0.f};
  f32x4 acc[4][4];
#pragma unroll
  for (int i = 0; i < 4; ++i)
#pragma unroll
    for (int j = 0; j < 4; ++j) acc[i][j] = vzero;

  for (int kt = 0; kt < 24; ++kt) {
    const int kb = kt * 32;
    const bf16x8 a0 = *(const bf16x8*)(gA0 + kb);
    const bf16x8 a1 = *(const bf16x8*)(gA1 + kb);
    const bf16x8 b0 = *(const bf16x8*)(gB0 + kb);
    const bf16x8 b1 = *(const bf16x8*)(gB1 + kb);
    __syncthreads();
    *(bf16x8*)&sA[rS][cS] = a0;
    *(bf16x8*)&sA[rS + 64][cS] = a1;
    *(bf16x8*)&sB[rS][cS] = b0;
    *(bf16x8*)&sB[rS + 64][cS] = b1;
    __syncthreads();
    bf16x8 av[4], bv[4];
#pragma unroll
    for (int i = 0; i < 4; ++i) av[i] = *(const bf16x8*)&sA[wr * 64 + i * 16 + lc][lg * 8];
#pragma unroll
    for (int jn = 0; jn < 4; ++jn) bv[jn] = *(const bf16x8*)&sB[wc * 64 + jn * 16 + lc][lg * 8];
#pragma unroll
    for (int i = 0; i < 4; ++i)
#pragma unroll
      for (int jn = 0; jn < 4; ++jn)
        acc[i][jn] = __builtin_amdgcn_mfma_f32_16x16x32_bf16(av[i], bv[jn], acc[i][jn], 0, 0, 0);
  }

  if constexpr (MODE == 0) {
    const float qsc = (blockIdx.y == 0) ? 0.14433756729740643f : 1.0f;  // 48^-0.5 folded into Q
#pragma unroll
    for (int i = 0; i < 4; ++i) {
      const int c0 = mbase + wr * 64 + i * 16 + lg * 4;
      const int hh = c0 / 48;
      const int d0 = c0 - hh * 48;
#pragma unroll
      for (int jn = 0; jn < 4; ++jn) {
        const int bn = nbase + wc * 64 + jn * 16 + lc;
        const int bb = bn / 576;
        const int nn = bn - bb * 576;
        ushort4 o;
        o.x = f2bf(acc[i][jn][0] * qsc); o.y = f2bf(acc[i][jn][1] * qsc);
        o.z = f2bf(acc[i][jn][2] * qsc); o.w = f2bf(acc[i][jn][3] * qsc);
        *(ushort4*)&ob[(((size_t)bb * 16 + hh) * 576 + nn) * 64 + d0] = o;
      }
    }
  } else if constexpr (MODE == 1) {
#pragma unroll
    for (int i = 0; i < 4; ++i) {
      const int bn0 = mbase + wr * 64 + i * 16 + lg * 4;
      const int bb = bn0 / 576;
      const int nn0 = bn0 - bb * 576;
#pragma unroll
      for (int jn = 0; jn < 4; ++jn) {
        const int c = nbase + wc * 64 + jn * 16 + lc;
        const int hh = c / 48;
        const int dd = c - hh * 48;
        ushort4 o;
        o.x = f2bf(acc[i][jn][0]); o.y = f2bf(acc[i][jn][1]);
        o.z = f2bf(acc[i][jn][2]); o.w = f2bf(acc[i][jn][3]);
        *(ushort4*)&ob[(((size_t)bb * 16 + hh) * 48 + dd) * 576 + nn0] = o;
      }
    }
  } else {
#pragma unroll
    for (int i = 0; i < 4; ++i) {
      const int c0 = mbase + wr * 64 + i * 16 + lg * 4;
      const float4 b4 = *(const float4*)&bias[c0];
#pragma unroll
      for (int jn = 0; jn < 4; ++jn) {
        const int bn = nbase + wc * 64 + jn * 16 + lc;
        float4 o;
        o.x = acc[i][jn][0] + b4.x; o.y = acc[i][jn][1] + b4.y;
        o.z = acc[i][jn][2] + b4.z; o.w = acc[i][jn][3] + b4.w;
        *(float4*)&of[(size_t)bn * 768 + c0] = o;
      }
    }
  }
}

// ---------------- fused gated attention ----------------
// Block = 4 waves: (q-half 0/1) x (k-split 0/1). 32 q-rows/block, k range split 2x288.
// Wave: 16 q-rows, 9 chunks of 32 keys, register-double-buffered K and posg fragments.
// Patch part accumulated unnormalized + row-sum l (scores bounded -> exp w/o max-sub);
// pos part is a straight PV MFMA on precomputed g*softmax (bf16). Final O =
// (1-g)*O_p/l + O_g after a 2-way LDS split-k reduction.
__global__ __launch_bounds__(256) void attn_fused(
    const u16* __restrict__ Q, const u16* __restrict__ K, const u16* __restrict__ VT,
    const u16* __restrict__ posg, const float* __restrict__ gating, u16* __restrict__ O) {
  const int qt = blockIdx.x, h = blockIdx.y, b = blockIdx.z;
  const int tid = threadIdx.x;
  const int w = tid >> 6, lane = tid & 63;
  const int qh = w >> 1, ks = w & 1;
  const int lg = lane >> 4, lc = lane & 15;
  const int bh = b * 16 + h;

  const u16* Qh = Q + (size_t)bh * 576 * 64;
  const u16* Kh = K + (size_t)bh * 576 * 64;
  const u16* Vh = VT + (size_t)bh * 48 * 576;
  const u16* Gh = posg + (size_t)h * 576 * 576;

  __shared__ u16 pls[4][2][16][40];   // per-wave patch-P repack, parity double-buffered
  __shared__ float red[2][64][29];    // split-k reduction: 24 acc + 4 lsum, 29 stride (bank-free)

  const int qbase = qt * 32 + qh * 16;
  const bf16x8 aq0 = *(const bf16x8*)&Qh[(qbase + lc) * 64 + lg * 8];
  const bf16x8 aq1 = *(const bf16x8*)&Qh[(qbase + lc) * 64 + lg * 8 + 32];

  const int kbase = ks * 288;
  const u16* Gq = Gh + (size_t)(qbase + lc) * 576;

  bf16x8 kb[2][2][2];  // [buf][t][dhalf]
  bf16x8 gab[2];
#pragma unroll
  for (int t = 0; t < 2; ++t) {
    kb[0][t][0] = *(const bf16x8*)&Kh[(kbase + t * 16 + lc) * 64 + lg * 8];
    kb[0][t][1] = *(const bf16x8*)&Kh[(kbase + t * 16 + lc) * 64 + lg * 8 + 32];
  }
  gab[0] = *(const bf16x8*)&Gq[kbase + lg * 8];

  const f32x4 vzero = {0.f, 0.f, 0.f, 0.f};
  f32x4 accP[3], accG[3];
#pragma unroll
  for (int dt = 0; dt < 3; ++dt) { accP[dt] = vzero; accG[dt] = vzero; }
  float lsum[4] = {0.f, 0.f, 0.f, 0.f};

#pragma unroll
  for (int kc = 0; kc < 9; ++kc) {
    const int cur = kc & 1;
    const int k0 = kbase + kc * 32;
    if (kc < 8) {  // prefetch next chunk (K + posg) into the other buffer
      const int k1 = k0 + 32;
#pragma unroll
      for (int t = 0; t < 2; ++t) {
        kb[cur ^ 1][t][0] = *(const bf16x8*)&Kh[(k1 + t * 16 + lc) * 64 + lg * 8];
        kb[cur ^ 1][t][1] = *(const bf16x8*)&Kh[(k1 + t * 16 + lc) * 64 + lg * 8 + 32];
      }
      gab[cur ^ 1] = *(const bf16x8*)&Gq[k1 + lg * 8];
    }
    // V fragments for this chunk (issued early; consumed after QK+exp)
    const bf16x8 vb0 = *(const bf16x8*)&Vh[(0 * 16 + lc) * 576 + k0 + lg * 8];
    const bf16x8 vb1 = *(const bf16x8*)&Vh[(1 * 16 + lc) * 576 + k0 + lg * 8];
    const bf16x8 vb2 = *(const bf16x8*)&Vh[(2 * 16 + lc) * 576 + k0 + lg * 8];

    f32x4 s0 = vzero, s1 = vzero;
    s0 = __builtin_amdgcn_mfma_f32_16x16x32_bf16(aq0, kb[cur][0][0], s0, 0, 0, 0);
    s0 = __builtin_amdgcn_mfma_f32_16x16x32_bf16(aq1, kb[cur][0][1], s0, 0, 0, 0);
    s1 = __builtin_amdgcn_mfma_f32_16x16x32_bf16(aq0, kb[cur][1][0], s1, 0, 0, 0);
    s1 = __builtin_amdgcn_mfma_f32_16x16x32_bf16(aq1, kb[cur][1][1], s1, 0, 0, 0);

#pragma unroll
    for (int j = 0; j < 4; ++j) {  // D row = lg*4+j, cols t*16+lc
      const float p0 = __expf(s0[j]);
      const float p1 = __expf(s1[j]);
      lsum[j] += p0 + p1;
      pls[w][cur][lg * 4 + j][lc] = f2bf(p0);
      pls[w][cur][lg * 4 + j][16 + lc] = f2bf(p1);
    }
    asm volatile("s_waitcnt lgkmcnt(0)" ::: "memory");  // wave-private LDS write->read
    const bf16x8 pa = *(const bf16x8*)&pls[w][cur][lc][lg * 8];
    accP[0] = __builtin_amdgcn_mfma_f32_16x16x32_bf16(pa, vb0, accP[0], 0, 0, 0);
    accG[0] = __builtin_amdgcn_mfma_f32_16x16x32_bf16(gab[cur], vb0, accG[0], 0, 0, 0);
    accP[1] = __builtin_amdgcn_mfma_f32_16x16x32_bf16(pa, vb1, accP[1], 0, 0, 0);
    accG[1] = __builtin_amdgcn_mfma_f32_16x16x32_bf16(gab[cur], vb1, accG[1], 0, 0, 0);
    accP[2] = __builtin_amdgcn_mfma_f32_16x16x32_bf16(pa, vb2, accP[2], 0, 0, 0);
    accG[2] = __builtin_amdgcn_mfma_f32_16x16x32_bf16(gab[cur], vb2, accG[2], 0, 0, 0);
  }

  // partial row-sums (reduce across lc within each lg group)
  float lred[4];
#pragma unroll
  for (int j = 0; j < 4; ++j) {
    float sv = lsum[j];
    sv += __shfl_xor(sv, 1, 64);
    sv += __shfl_xor(sv, 2, 64);
    sv += __shfl_xor(sv, 4, 64);
    sv += __shfl_xor(sv, 8, 64);
    lred[j] = sv;
  }

  // split-k combine: ks=1 publishes, ks=0 reduces + writes
  if (ks == 1) {
#pragma unroll
    for (int dt = 0; dt < 3; ++dt)
#pragma unroll
      for (int j = 0; j < 4; ++j) {
        red[qh][lane][dt * 4 + j] = accP[dt][j];
        red[qh][lane][12 + dt * 4 + j] = accG[dt][j];
      }
#pragma unroll
    for (int j = 0; j < 4; ++j) red[qh][lane][24 + j] = lred[j];
  }
  __syncthreads();
  if (ks == 0) {
    const float g = 1.f / (1.f + __expf(-gating[h]));
    const float omg = 1.f - g;
    float linv[4];
#pragma unroll
    for (int j = 0; j < 4; ++j) linv[j] = 1.f / (lred[j] + red[qh][lane][24 + j]);
#pragma unroll
    for (int dt = 0; dt < 3; ++dt) {
#pragma unroll
      for (int j = 0; j < 4; ++j) {
        const float p = accP[dt][j] + red[qh][lane][dt * 4 + j];
        const float gg = accG[dt][j] + red[qh][lane][12 + dt * 4 + j];
        const float val = omg * p * linv[j] + gg;
        const int qg = qbase + lg * 4 + j;
        O[((size_t)(b * 576 + qg)) * 768 + h * 48 + dt * 16 + lc] = f2bf(val);
      }
    }
  }
}

// ---------------- launch ----------------
extern "C" void kernel_launch(void* const* d_in, const int* in_sizes, int n_in,
                              void* d_out, int out_size, void* d_ws, size_t ws_size,
                              hipStream_t stream) {
  const float* x      = (const float*)d_in[0];
  const float* Wq     = (const float*)d_in[1];
  const float* Wk     = (const float*)d_in[2];
  const float* Wv     = (const float*)d_in[3];
  const float* Wp     = (const float*)d_in[4];
  const float* bproj  = (const float*)d_in[5];
  const float* Wpos   = (const float*)d_in[6];
  const float* bpos   = (const float*)d_in[7];
  const float* gating = (const float*)d_in[8];
  float* out = (float*)d_out;

  char* ws = (char*)d_ws;
  u16* xb      = (u16*)(ws + 0);
  u16* wqb     = (u16*)(ws + 7077888);
  u16* wkb     = (u16*)(ws + 8257536);
  u16* wvb     = (u16*)(ws + 9437184);
  u16* wpb     = (u16*)(ws + 10616832);
  u16* Qw      = (u16*)(ws + 11796480);
  u16* Kw      = (u16*)(ws + 21233664);
  u16* VTw     = (u16*)(ws + 30670848);
  u16* Ow      = (u16*)(ws + 37748736);
  u16* posg    = (u16*)(ws + 0);  // overlays xb/wqb/wkb/wvb: dead after QKV GEMMs

  cvt_f32_bf16<<<dim3(3456), dim3(256), 0, stream>>>(x, xb, 884736);
  cvt_w4<<<dim3(576, 4), dim3(256), 0, stream>>>(Wq, Wk, Wv, Wp, wqb);
  // zero Q+K (contiguous) so head-dim pad 48..63 is zero for the K=64 MFMA
  hipMemsetAsync(Qw, 0, 18874368, stream);
  gemm_bt<0><<<dim3(216, 2), dim3(256), 0, stream>>>(wqb, wkb, xb, Qw, Kw, nullptr, nullptr, 36);
  gemm_bt<1><<<dim3(216, 1), dim3(256), 0, stream>>>(xb, xb, wvb, VTw, VTw, nullptr, nullptr, 6);
  pos_soft<<<dim3(2304), dim3(256), 0, stream>>>(Wpos, bpos, gating, posg);  // xb region now dead
  attn_fused<<<dim3(18, 16, 8), dim3(256), 0, stream>>>(Qw, Kw, VTw, posg, gating, Ow);
  gemm_bt<2><<<dim3(216, 1), dim3(256), 0, stream>>>(wpb, wpb, Ow, nullptr, nullptr, out, bproj, 36);
}

// Round 3
// 164.456 us; speedup vs baseline: 1.0379x; 1.0334x over previous
//
#include <hip/hip_runtime.h>
#include <hip/hip_bf16.h>
#include <cstdint>

// ConViT GPSA fused pipeline, bf16 MFMA throughout.
// ws (~44.9 MB): xb(7.08M) wqb/wkb/wvb/wpb(1.18M ea) Q(9.44M) K(9.44M) VT(7.08M) O(7.08M)
// posg(10.6M) overlays [xb..wvb] after gemm_qkv consumes them (wpb at 10,616,832 survives).

typedef unsigned short u16;
typedef __attribute__((ext_vector_type(8))) short bf16x8;
typedef __attribute__((ext_vector_type(4))) float f32x4;

__device__ __forceinline__ u16 f2bf(float f) {
  union { float f; uint32_t u; } v; v.f = f;
  uint32_t r = v.u + 0x7FFFu + ((v.u >> 16) & 1u);  // RNE (no NaN in this workload)
  return (u16)(r >> 16);
}
__device__ __forceinline__ float bf2f(u16 u) {
  union { uint32_t u; float f; } v; v.u = ((uint32_t)u) << 16;
  return v.f;
}

// ---------------- f32 -> bf16: x + all 4 weights in one dispatch ----------------
__global__ __launch_bounds__(256) void cvt_all(const float* __restrict__ x,
                                               const float* __restrict__ Wq,
                                               const float* __restrict__ Wk,
                                               const float* __restrict__ Wv,
                                               const float* __restrict__ Wp,
                                               u16* __restrict__ dst) {
  const int i = blockIdx.x * 256 + threadIdx.x;  // 1,474,560 float4 items exactly
  const float* s;
  if (i < 884736) {
    s = x + (size_t)i * 4;
  } else {
    const int j = i - 884736;
    if (j < 147456) s = Wq + (size_t)j * 4;
    else if (j < 294912) s = Wk + (size_t)(j - 147456) * 4;
    else if (j < 442368) s = Wv + (size_t)(j - 294912) * 4;
    else s = Wp + (size_t)(j - 442368) * 4;
  }
  const float4 v = *(const float4*)s;
  ushort4 o;
  o.x = f2bf(v.x); o.y = f2bf(v.y); o.z = f2bf(v.z); o.w = f2bf(v.w);
  ((ushort4*)dst)[i] = o;
}

// ---------------- g-scaled positional softmax, materialized ----------------
// posg[h*576+n][m] = sigmoid(gating[h]) * softmax_m(W0*dx + W1*dy + W2*dd + bpos[h])
__global__ __launch_bounds__(256) void pos_soft(const float* __restrict__ Wpos,
                                                const float* __restrict__ bpos,
                                                const float* __restrict__ gating,
                                                u16* __restrict__ posg) {
  const int w = threadIdx.x >> 6, lane = threadIdx.x & 63;
  const int row = blockIdx.x * 4 + w;            // 0..9215  (h*576+n)
  const int h = row / 576, n = row - h * 576;
  const float w0 = Wpos[h * 3 + 0], w1 = Wpos[h * 3 + 1], w2 = Wpos[h * 3 + 2], bp = bpos[h];
  const float g = 1.f / (1.f + __expf(-gating[h]));
  const int qr = n / 24, qc = n - qr * 24;
  float vals[9], evals[9];
  float mx = -1e30f;
#pragma unroll
  for (int i = 0; i < 9; ++i) {
    const int m = i * 64 + lane;
    const int kr = m / 24, kc = m - kr * 24;
    const float dx = (float)(kc - qc), dy = (float)(kr - qr);
    const float p = w0 * dx + w1 * dy + w2 * (dx * dx + dy * dy) + bp;
    vals[i] = p;
    mx = fmaxf(mx, p);
  }
#pragma unroll
  for (int off = 1; off < 64; off <<= 1) mx = fmaxf(mx, __shfl_xor(mx, off, 64));
  float s = 0.f;
#pragma unroll
  for (int i = 0; i < 9; ++i) { evals[i] = __expf(vals[i] - mx); s += evals[i]; }
#pragma unroll
  for (int off = 1; off < 64; off <<= 1) s += __shfl_xor(s, off, 64);
  const float gi = g / s;
  u16* out = posg + (size_t)row * 576;
#pragma unroll
  for (int i = 0; i < 9; ++i) out[i * 64 + lane] = f2bf(evals[i] * gi);
}

// ---------------- unified QKV projection (C = W @ x^T per mode), K = 768 ----------------
// blockIdx.y: 0 -> Q (scaled by 48^-0.5), 1 -> K, 2 -> V.
// Q/K written as (bh, n, 64-stride) bf16 (pad d 48..63 left untouched; attn zeroes in-reg).
// V written transposed as (bh, d, 576) bf16.
__global__ __launch_bounds__(256) void gemm_qkv(
    const u16* __restrict__ wq, const u16* __restrict__ wk, const u16* __restrict__ wv,
    const u16* __restrict__ xb, u16* __restrict__ Qo, u16* __restrict__ Ko,
    u16* __restrict__ Vo) {
  __shared__ u16 sA[128][40];
  __shared__ u16 sB[128][40];

  const int y = blockIdx.y;
  const u16* A = y == 0 ? wq : y == 1 ? wk : wv;

  const int mt = blockIdx.x / 36, nt = blockIdx.x % 36;
  const int mbase = mt * 128, nbase = nt * 128;
  const int tid = threadIdx.x;
  const int w = tid >> 6, lane = tid & 63;
  const int wr = w >> 1, wc = w & 1;
  const int lg = lane >> 4, lc = lane & 15;
  const int rS = tid >> 2;
  const int cS = (tid & 3) * 8;

  const u16* gA0 = A + (size_t)(mbase + rS) * 768 + cS;
  const u16* gA1 = gA0 + (size_t)64 * 768;
  const u16* gB0 = xb + (size_t)(nbase + rS) * 768 + cS;
  const u16* gB1 = gB0 + (size_t)64 * 768;

  const f32x4 vzero = {0.f, 0.f, 0.f, 0.f};
  f32x4 acc[4][4];
#pragma unroll
  for (int i = 0; i < 4; ++i)
#pragma unroll
    for (int j = 0; j < 4; ++j) acc[i][j] = vzero;

  for (int kt = 0; kt < 24; ++kt) {
    const int kb = kt * 32;
    const bf16x8 a0 = *(const bf16x8*)(gA0 + kb);
    const bf16x8 a1 = *(const bf16x8*)(gA1 + kb);
    const bf16x8 b0 = *(const bf16x8*)(gB0 + kb);
    const bf16x8 b1 = *(const bf16x8*)(gB1 + kb);
    __syncthreads();
    *(bf16x8*)&sA[rS][cS] = a0;
    *(bf16x8*)&sA[rS + 64][cS] = a1;
    *(bf16x8*)&sB[rS][cS] = b0;
    *(bf16x8*)&sB[rS + 64][cS] = b1;
    __syncthreads();
    bf16x8 av[4], bv[4];
#pragma unroll
    for (int i = 0; i < 4; ++i) av[i] = *(const bf16x8*)&sA[wr * 64 + i * 16 + lc][lg * 8];
#pragma unroll
    for (int jn = 0; jn < 4; ++jn) bv[jn] = *(const bf16x8*)&sB[wc * 64 + jn * 16 + lc][lg * 8];
#pragma unroll
    for (int i = 0; i < 4; ++i)
#pragma unroll
      for (int jn = 0; jn < 4; ++jn)
        acc[i][jn] = __builtin_amdgcn_mfma_f32_16x16x32_bf16(av[i], bv[jn], acc[i][jn], 0, 0, 0);
  }

  if (y < 2) {
    const float qsc = (y == 0) ? 0.14433756729740643f : 1.0f;  // 48^-0.5 folded into Q
    u16* ob = (y == 0) ? Qo : Ko;
#pragma unroll
    for (int i = 0; i < 4; ++i) {
      const int c0 = mbase + wr * 64 + i * 16 + lg * 4;
      const int hh = c0 / 48;
      const int d0 = c0 - hh * 48;
#pragma unroll
      for (int jn = 0; jn < 4; ++jn) {
        const int bn = nbase + wc * 64 + jn * 16 + lc;
        const int bb = bn / 576;
        const int nn = bn - bb * 576;
        ushort4 o;
        o.x = f2bf(acc[i][jn][0] * qsc); o.y = f2bf(acc[i][jn][1] * qsc);
        o.z = f2bf(acc[i][jn][2] * qsc); o.w = f2bf(acc[i][jn][3] * qsc);
        *(ushort4*)&ob[(((size_t)bb * 16 + hh) * 576 + nn) * 64 + d0] = o;
      }
    }
  } else {
#pragma unroll
    for (int i = 0; i < 4; ++i) {
      const int c0 = mbase + wr * 64 + i * 16 + lg * 4;
      const int hh = c0 / 48;
      const int d0 = c0 - hh * 48;
#pragma unroll
      for (int jn = 0; jn < 4; ++jn) {
        const int bn = nbase + wc * 64 + jn * 16 + lc;
        const int bb = bn / 576;
        const int nn = bn - bb * 576;
#pragma unroll
        for (int j = 0; j < 4; ++j)
          Vo[(((size_t)bb * 16 + hh) * 48 + d0 + j) * 576 + nn] = f2bf(acc[i][jn][j]);
      }
    }
  }
}

// ---------------- pos-attention GEMM: Og[b,h,q,d] = sum_m V[b,m,d] * posg[h,q,m] ----------------
// A = Vcat (384 rows: (b,d)), B = posg rows q (640 w/ guard), K = 576. Writes g*O_pos into Ow.
__global__ __launch_bounds__(256) void pos_gemm(const u16* __restrict__ VT,
                                                const u16* __restrict__ posg,
                                                u16* __restrict__ O) {
  __shared__ u16 sA[128][40];
  __shared__ u16 sB[128][40];

  const int h = blockIdx.y;
  const int mt = blockIdx.x / 5, nt = blockIdx.x % 5;
  const int mbase = mt * 128, nbase = nt * 128;
  const int tid = threadIdx.x;
  const int w = tid >> 6, lane = tid & 63;
  const int wr = w >> 1, wc = w & 1;
  const int lg = lane >> 4, lc = lane & 15;
  const int rS = tid >> 2;
  const int cS = (tid & 3) * 8;

  const int mA0 = mbase + rS, mA1 = mA0 + 64;
  const u16* gA0 = VT + ((size_t)((mA0 / 48) * 16 + h) * 48 + (mA0 % 48)) * 576 + cS;
  const u16* gA1 = VT + ((size_t)((mA1 / 48) * 16 + h) * 48 + (mA1 % 48)) * 576 + cS;
  const u16* gB0 = posg + (size_t)(h * 576 + nbase + rS) * 576 + cS;
  const u16* gB1 = gB0 + (size_t)64 * 576;

  const f32x4 vzero = {0.f, 0.f, 0.f, 0.f};
  f32x4 acc[4][4];
#pragma unroll
  for (int i = 0; i < 4; ++i)
#pragma unroll
    for (int j = 0; j < 4; ++j) acc[i][j] = vzero;

  for (int kt = 0; kt < 18; ++kt) {
    const int kb = kt * 32;
    const bf16x8 a0 = *(const bf16x8*)(gA0 + kb);
    const bf16x8 a1 = *(const bf16x8*)(gA1 + kb);
    const bf16x8 b0 = *(const bf16x8*)(gB0 + kb);
    const bf16x8 b1 = *(const bf16x8*)(gB1 + kb);
    __syncthreads();
    *(bf16x8*)&sA[rS][cS] = a0;
    *(bf16x8*)&sA[rS + 64][cS] = a1;
    *(bf16x8*)&sB[rS][cS] = b0;
    *(bf16x8*)&sB[rS + 64][cS] = b1;
    __syncthreads();
    bf16x8 av[4], bv[4];
#pragma unroll
    for (int i = 0; i < 4; ++i) av[i] = *(const bf16x8*)&sA[wr * 64 + i * 16 + lc][lg * 8];
#pragma unroll
    for (int jn = 0; jn < 4; ++jn) bv[jn] = *(const bf16x8*)&sB[wc * 64 + jn * 16 + lc][lg * 8];
#pragma unroll
    for (int i = 0; i < 4; ++i)
#pragma unroll
      for (int jn = 0; jn < 4; ++jn)
        acc[i][jn] = __builtin_amdgcn_mfma_f32_16x16x32_bf16(av[i], bv[jn], acc[i][jn], 0, 0, 0);
  }

#pragma unroll
  for (int i = 0; i < 4; ++i) {
    const int c0 = mbase + wr * 64 + i * 16 + lg * 4;  // (b,d): 4 consecutive d in one head
    const int bb = c0 / 48;
    const int d0 = c0 - bb * 48;
#pragma unroll
    for (int jn = 0; jn < 4; ++jn) {
      const int q = nbase + wc * 64 + jn * 16 + lc;
      if (q < 576) {
        ushort4 o;
        o.x = f2bf(acc[i][jn][0]); o.y = f2bf(acc[i][jn][1]);
        o.z = f2bf(acc[i][jn][2]); o.w = f2bf(acc[i][jn][3]);
        *(ushort4*)&O[((size_t)(bb * 576 + q)) * 768 + h * 48 + d0] = o;
      }
    }
  }
}

// ---------------- fused patch attention (pos part pre-added in Ow) ----------------
// Block = 4 waves: (q-half 0/1) x (k-split 0/1). 1-deep pipeline: PV(kc-1) overlaps exp(kc).
__global__ __launch_bounds__(256) void attn_fused(
    const u16* __restrict__ Q, const u16* __restrict__ K, const u16* __restrict__ VT,
    const float* __restrict__ gating, u16* __restrict__ O) {
  const int qt = blockIdx.x, h = blockIdx.y, b = blockIdx.z;
  const int tid = threadIdx.x;
  const int w = tid >> 6, lane = tid & 63;
  const int qh = w >> 1, ks = w & 1;
  const int lg = lane >> 4, lc = lane & 15;
  const int bh = b * 16 + h;

  const u16* Qh = Q + (size_t)bh * 576 * 64;
  const u16* Kh = K + (size_t)bh * 576 * 64;
  const u16* Vh = VT + (size_t)bh * 48 * 576;

  __shared__ u16 pls[4][2][16][40];   // per-wave patch-P repack, parity double-buffered
  __shared__ float red[2][64][17];    // split-k: 12 acc + 4 lsum

  const bf16x8 zer = {0, 0, 0, 0, 0, 0, 0, 0};
  const int qbase = qt * 32 + qh * 16;
  const bf16x8 aq0 = *(const bf16x8*)&Qh[(qbase + lc) * 64 + lg * 8];
  bf16x8 aq1 = zer;  // d 48..63 pad: zero in-register (both operands) instead of memset
  if (lg < 2) aq1 = *(const bf16x8*)&Qh[(qbase + lc) * 64 + lg * 8 + 32];

  const int kbase = ks * 288;

  bf16x8 kb[2][2][2];  // [buf][t][dhalf]
#pragma unroll
  for (int t = 0; t < 2; ++t) {
    kb[0][t][0] = *(const bf16x8*)&Kh[(kbase + t * 16 + lc) * 64 + lg * 8];
    kb[0][t][1] = zer;
    if (lg < 2) kb[0][t][1] = *(const bf16x8*)&Kh[(kbase + t * 16 + lc) * 64 + lg * 8 + 32];
  }

  const f32x4 vzero = {0.f, 0.f, 0.f, 0.f};
  f32x4 accP0 = vzero, accP1 = vzero, accP2 = vzero;
  float lsum[4] = {0.f, 0.f, 0.f, 0.f};
  bf16x8 paP = zer, vp0 = zer, vp1 = zer, vp2 = zer;

#pragma unroll
  for (int kc = 0; kc < 9; ++kc) {
    const int cur = kc & 1;
    const int k0 = kbase + kc * 32;
    if (kc < 8) {  // prefetch next K chunk
      const int k1 = k0 + 32;
#pragma unroll
      for (int t = 0; t < 2; ++t) {
        kb[cur ^ 1][t][0] = *(const bf16x8*)&Kh[(k1 + t * 16 + lc) * 64 + lg * 8];
        kb[cur ^ 1][t][1] = zer;
        if (lg < 2) kb[cur ^ 1][t][1] = *(const bf16x8*)&Kh[(k1 + t * 16 + lc) * 64 + lg * 8 + 32];
      }
    }
    // V for this chunk (consumed NEXT iteration -> full chunk of latency slack)
    const bf16x8 vb0 = *(const bf16x8*)&Vh[lc * 576 + k0 + lg * 8];
    const bf16x8 vb1 = *(const bf16x8*)&Vh[(16 + lc) * 576 + k0 + lg * 8];
    const bf16x8 vb2 = *(const bf16x8*)&Vh[(32 + lc) * 576 + k0 + lg * 8];

    f32x4 s0 = vzero, s1 = vzero;
    s0 = __builtin_amdgcn_mfma_f32_16x16x32_bf16(aq0, kb[cur][0][0], s0, 0, 0, 0);
    s0 = __builtin_amdgcn_mfma_f32_16x16x32_bf16(aq1, kb[cur][0][1], s0, 0, 0, 0);
    s1 = __builtin_amdgcn_mfma_f32_16x16x32_bf16(aq0, kb[cur][1][0], s1, 0, 0, 0);
    s1 = __builtin_amdgcn_mfma_f32_16x16x32_bf16(aq1, kb[cur][1][1], s1, 0, 0, 0);

    if (kc > 0) {  // PV of previous chunk: fills MFMA pipe while s0/s1 settle
      accP0 = __builtin_amdgcn_mfma_f32_16x16x32_bf16(paP, vp0, accP0, 0, 0, 0);
      accP1 = __builtin_amdgcn_mfma_f32_16x16x32_bf16(paP, vp1, accP1, 0, 0, 0);
      accP2 = __builtin_amdgcn_mfma_f32_16x16x32_bf16(paP, vp2, accP2, 0, 0, 0);
    }

#pragma unroll
    for (int j = 0; j < 4; ++j) {  // D row = lg*4+j, cols t*16+lc
      const float p0 = __expf(s0[j]);
      const float p1 = __expf(s1[j]);
      lsum[j] += p0 + p1;
      pls[w][cur][lg * 4 + j][lc] = f2bf(p0);
      pls[w][cur][lg * 4 + j][16 + lc] = f2bf(p1);
    }
    asm volatile("s_waitcnt lgkmcnt(0)" ::: "memory");  // wave-private LDS write->read
    paP = *(const bf16x8*)&pls[w][cur][lc][lg * 8];
    vp0 = vb0; vp1 = vb1; vp2 = vb2;
  }
  accP0 = __builtin_amdgcn_mfma_f32_16x16x32_bf16(paP, vp0, accP0, 0, 0, 0);
  accP1 = __builtin_amdgcn_mfma_f32_16x16x32_bf16(paP, vp1, accP1, 0, 0, 0);
  accP2 = __builtin_amdgcn_mfma_f32_16x16x32_bf16(paP, vp2, accP2, 0, 0, 0);

  float lred[4];
#pragma unroll
  for (int j = 0; j < 4; ++j) {
    float sv = lsum[j];
    sv += __shfl_xor(sv, 1, 64);
    sv += __shfl_xor(sv, 2, 64);
    sv += __shfl_xor(sv, 4, 64);
    sv += __shfl_xor(sv, 8, 64);
    lred[j] = sv;
  }

  if (ks == 1) {
#pragma unroll
    for (int j = 0; j < 4; ++j) {
      red[qh][lane][0 + j] = accP0[j];
      red[qh][lane][4 + j] = accP1[j];
      red[qh][lane][8 + j] = accP2[j];
      red[qh][lane][12 + j] = lred[j];
    }
  }
  __syncthreads();
  if (ks == 0) {
    const float g = 1.f / (1.f + __expf(-gating[h]));
    const float omg = 1.f - g;
    float linv[4];
#pragma unroll
    for (int j = 0; j < 4; ++j) linv[j] = omg / (lred[j] + red[qh][lane][12 + j]);
#pragma unroll
    for (int dt = 0; dt < 3; ++dt) {
#pragma unroll
      for (int j = 0; j < 4; ++j) {
        const float p = (dt == 0 ? accP0[j] : dt == 1 ? accP1[j] : accP2[j]) +
                        red[qh][lane][dt * 4 + j];
        const int qg = qbase + lg * 4 + j;
        const size_t idx = ((size_t)(b * 576 + qg)) * 768 + h * 48 + dt * 16 + lc;
        const float val = p * linv[j] + bf2f(O[idx]);  // add pre-computed g*O_pos
        O[idx] = f2bf(val);
      }
    }
  }
}

// ---------------- output projection: out = O @ Wproj^T + b ----------------
__global__ __launch_bounds__(256) void gemm_proj(const u16* __restrict__ A,
                                                 const u16* __restrict__ B,
                                                 float* __restrict__ of,
                                                 const float* __restrict__ bias) {
  __shared__ u16 sA[128][40];
  __shared__ u16 sB[128][40];

  const int mt = blockIdx.x / 36, nt = blockIdx.x % 36;
  const int mbase = mt * 128, nbase = nt * 128;
  const int tid = threadIdx.x;
  const int w = tid >> 6, lane = tid & 63;
  const int wr = w >> 1, wc = w & 1;
  const int lg = lane >> 4, lc = lane & 15;
  const int rS = tid >> 2;
  const int cS = (tid & 3) * 8;

  const u16* gA0 = A + (size_t)(mbase + rS) * 768 + cS;
  const u16* gA1 = gA0 + (size_t)64 * 768;
  const u16* gB0 = B + (size_t)(nbase + rS) * 768 + cS;
  const u16* gB1 = gB0 + (size_t)64 * 768;

  const f32x4 vzero = {0.f, 0.f, 0.f, 0.f};
  f32x4 acc[4][4];
#pragma unroll
  for (int i = 0; i < 4; ++i)
#pragma unroll
    for (int j = 0; j < 4; ++j) acc[i][j] = vzero;

  for (int kt = 0; kt < 24; ++kt) {
    const int kb = kt * 32;
    const bf16x8 a0 = *(const bf16x8*)(gA0 + kb);
    const bf16x8 a1 = *(const bf16x8*)(gA1 + kb);
    const bf16x8 b0 = *(const bf16x8*)(gB0 + kb);
    const bf16x8 b1 = *(const bf16x8*)(gB1 + kb);
    __syncthreads();
    *(bf16x8*)&sA[rS][cS] = a0;
    *(bf16x8*)&sA[rS + 64][cS] = a1;
    *(bf16x8*)&sB[rS][cS] = b0;
    *(bf16x8*)&sB[rS + 64][cS] = b1;
    __syncthreads();
    bf16x8 av[4], bv[4];
#pragma unroll
    for (int i = 0; i < 4; ++i) av[i] = *(const bf16x8*)&sA[wr * 64 + i * 16 + lc][lg * 8];
#pragma unroll
    for (int jn = 0; jn < 4; ++jn) bv[jn] = *(const bf16x8*)&sB[wc * 64 + jn * 16 + lc][lg * 8];
#pragma unroll
    for (int i = 0; i < 4; ++i)
#pragma unroll
      for (int jn = 0; jn < 4; ++jn)
        acc[i][jn] = __builtin_amdgcn_mfma_f32_16x16x32_bf16(av[i], bv[jn], acc[i][jn], 0, 0, 0);
  }

#pragma unroll
  for (int i = 0; i < 4; ++i) {
    const int c0 = mbase + wr * 64 + i * 16 + lg * 4;
    const float4 b4 = *(const float4*)&bias[c0];
#pragma unroll
    for (int jn = 0; jn < 4; ++jn) {
      const int bn = nbase + wc * 64 + jn * 16 + lc;
      float4 o;
      o.x = acc[i][jn][0] + b4.x; o.y = acc[i][jn][1] + b4.y;
      o.z = acc[i][jn][2] + b4.z; o.w = acc[i][jn][3] + b4.w;
      *(float4*)&of[(size_t)bn * 768 + c0] = o;
    }
  }
}

// ---------------- launch ----------------
extern "C" void kernel_launch(void* const* d_in, const int* in_sizes, int n_in,
                              void* d_out, int out_size, void* d_ws, size_t ws_size,
                              hipStream_t stream) {
  const float* x      = (const float*)d_in[0];
  const float* Wq     = (const float*)d_in[1];
  const float* Wk     = (const float*)d_in[2];
  const float* Wv     = (const float*)d_in[3];
  const float* Wp     = (const float*)d_in[4];
  const float* bproj  = (const float*)d_in[5];
  const float* Wpos   = (const float*)d_in[6];
  const float* bpos   = (const float*)d_in[7];
  const float* gating = (const float*)d_in[8];
  float* out = (float*)d_out;

  char* ws = (char*)d_ws;
  u16* xb   = (u16*)(ws + 0);
  u16* wqb  = (u16*)(ws + 7077888);
  u16* wkb  = (u16*)(ws + 8257536);
  u16* wvb  = (u16*)(ws + 9437184);
  u16* wpb  = (u16*)(ws + 10616832);
  u16* Qw   = (u16*)(ws + 11796480);
  u16* Kw   = (u16*)(ws + 21233664);
  u16* VTw  = (u16*)(ws + 30670848);
  u16* Ow   = (u16*)(ws + 37748736);
  u16* posg = (u16*)(ws + 0);  // overlays xb..wvb (dead after gemm_qkv); ends exactly at wpb

  cvt_all<<<dim3(5760), dim3(256), 0, stream>>>(x, Wq, Wk, Wv, Wp, xb);
  gemm_qkv<<<dim3(216, 3), dim3(256), 0, stream>>>(wqb, wkb, wvb, xb, Qw, Kw, VTw);
  pos_soft<<<dim3(2304), dim3(256), 0, stream>>>(Wpos, bpos, gating, posg);
  pos_gemm<<<dim3(15, 16), dim3(256), 0, stream>>>(VTw, posg, Ow);
  attn_fused<<<dim3(18, 16, 8), dim3(256), 0, stream>>>(Qw, Kw, VTw, gating, Ow);
  gemm_proj<<<dim3(216), dim3(256), 0, stream>>>(wpb, Ow, out, bproj);
}

// Round 4
// 158.788 us; speedup vs baseline: 1.0749x; 1.0357x over previous
//
#include <hip/hip_runtime.h>
#include <hip/hip_bf16.h>
#include <cstdint>

// ConViT GPSA fused pipeline, bf16 MFMA throughout.
// ws (~44.9 MB): xb(7.08M) wqb/wkb/wvb/wpb(1.18M ea) Q(9.44M) K(9.44M) VT(7.08M) O(7.08M)
// posg(10.6M) overlays [xb..wvb] after gemm_qkv consumes them (wpb at 10,616,832 survives).

typedef unsigned short u16;
typedef __attribute__((ext_vector_type(8))) short bf16x8;
typedef __attribute__((ext_vector_type(4))) float f32x4;

__device__ __forceinline__ u16 f2bf(float f) {
  union { float f; uint32_t u; } v; v.f = f;
  uint32_t r = v.u + 0x7FFFu + ((v.u >> 16) & 1u);  // RNE (no NaN in this workload)
  return (u16)(r >> 16);
}
__device__ __forceinline__ float bf2f(u16 u) {
  union { uint32_t u; float f; } v; v.u = ((uint32_t)u) << 16;
  return v.f;
}

// ---------------- f32 -> bf16: x + all 4 weights in one dispatch ----------------
__global__ __launch_bounds__(256) void cvt_all(const float* __restrict__ x,
                                               const float* __restrict__ Wq,
                                               const float* __restrict__ Wk,
                                               const float* __restrict__ Wv,
                                               const float* __restrict__ Wp,
                                               u16* __restrict__ dst) {
  const int i = blockIdx.x * 256 + threadIdx.x;  // 1,474,560 float4 items exactly
  const float* s;
  if (i < 884736) {
    s = x + (size_t)i * 4;
  } else {
    const int j = i - 884736;
    if (j < 147456) s = Wq + (size_t)j * 4;
    else if (j < 294912) s = Wk + (size_t)(j - 147456) * 4;
    else if (j < 442368) s = Wv + (size_t)(j - 294912) * 4;
    else s = Wp + (size_t)(j - 442368) * 4;
  }
  const float4 v = *(const float4*)s;
  ushort4 o;
  o.x = f2bf(v.x); o.y = f2bf(v.y); o.z = f2bf(v.z); o.w = f2bf(v.w);
  ((ushort4*)dst)[i] = o;
}

// ---------------- g-scaled positional softmax, materialized ----------------
__global__ __launch_bounds__(256) void pos_soft(const float* __restrict__ Wpos,
                                                const float* __restrict__ bpos,
                                                const float* __restrict__ gating,
                                                u16* __restrict__ posg) {
  const int w = threadIdx.x >> 6, lane = threadIdx.x & 63;
  const int row = blockIdx.x * 4 + w;            // 0..9215  (h*576+n)
  const int h = row / 576, n = row - h * 576;
  const float w0 = Wpos[h * 3 + 0], w1 = Wpos[h * 3 + 1], w2 = Wpos[h * 3 + 2], bp = bpos[h];
  const float g = 1.f / (1.f + __expf(-gating[h]));
  const int qr = n / 24, qc = n - qr * 24;
  float vals[9], evals[9];
  float mx = -1e30f;
#pragma unroll
  for (int i = 0; i < 9; ++i) {
    const int m = i * 64 + lane;
    const int kr = m / 24, kc = m - kr * 24;
    const float dx = (float)(kc - qc), dy = (float)(kr - qr);
    const float p = w0 * dx + w1 * dy + w2 * (dx * dx + dy * dy) + bp;
    vals[i] = p;
    mx = fmaxf(mx, p);
  }
#pragma unroll
  for (int off = 1; off < 64; off <<= 1) mx = fmaxf(mx, __shfl_xor(mx, off, 64));
  float s = 0.f;
#pragma unroll
  for (int i = 0; i < 9; ++i) { evals[i] = __expf(vals[i] - mx); s += evals[i]; }
#pragma unroll
  for (int off = 1; off < 64; off <<= 1) s += __shfl_xor(s, off, 64);
  const float gi = g / s;
  u16* out = posg + (size_t)row * 576;
#pragma unroll
  for (int i = 0; i < 9; ++i) out[i * 64 + lane] = f2bf(evals[i] * gi);
}

// ---------------- unified QKV projection (C = W @ x^T per mode), K = 768 ----------------
__global__ __launch_bounds__(256) void gemm_qkv(
    const u16* __restrict__ wq, const u16* __restrict__ wk, const u16* __restrict__ wv,
    const u16* __restrict__ xb, u16* __restrict__ Qo, u16* __restrict__ Ko,
    u16* __restrict__ Vo) {
  __shared__ u16 sA[128][40];
  __shared__ u16 sB[128][40];

  const int y = blockIdx.y;
  const u16* A = y == 0 ? wq : y == 1 ? wk : wv;

  const int mt = blockIdx.x / 36, nt = blockIdx.x % 36;
  const int mbase = mt * 128, nbase = nt * 128;
  const int tid = threadIdx.x;
  const int w = tid >> 6, lane = tid & 63;
  const int wr = w >> 1, wc = w & 1;
  const int lg = lane >> 4, lc = lane & 15;
  const int rS = tid >> 2;
  const int cS = (tid & 3) * 8;

  const u16* gA0 = A + (size_t)(mbase + rS) * 768 + cS;
  const u16* gA1 = gA0 + (size_t)64 * 768;
  const u16* gB0 = xb + (size_t)(nbase + rS) * 768 + cS;
  const u16* gB1 = gB0 + (size_t)64 * 768;

  const f32x4 vzero = {0.f, 0.f, 0.f, 0.f};
  f32x4 acc[4][4];
#pragma unroll
  for (int i = 0; i < 4; ++i)
#pragma unroll
    for (int j = 0; j < 4; ++j) acc[i][j] = vzero;

  for (int kt = 0; kt < 24; ++kt) {
    const int kb = kt * 32;
    const bf16x8 a0 = *(const bf16x8*)(gA0 + kb);
    const bf16x8 a1 = *(const bf16x8*)(gA1 + kb);
    const bf16x8 b0 = *(const bf16x8*)(gB0 + kb);
    const bf16x8 b1 = *(const bf16x8*)(gB1 + kb);
    __syncthreads();
    *(bf16x8*)&sA[rS][cS] = a0;
    *(bf16x8*)&sA[rS + 64][cS] = a1;
    *(bf16x8*)&sB[rS][cS] = b0;
    *(bf16x8*)&sB[rS + 64][cS] = b1;
    __syncthreads();
    bf16x8 av[4], bv[4];
#pragma unroll
    for (int i = 0; i < 4; ++i) av[i] = *(const bf16x8*)&sA[wr * 64 + i * 16 + lc][lg * 8];
#pragma unroll
    for (int jn = 0; jn < 4; ++jn) bv[jn] = *(const bf16x8*)&sB[wc * 64 + jn * 16 + lc][lg * 8];
#pragma unroll
    for (int i = 0; i < 4; ++i)
#pragma unroll
      for (int jn = 0; jn < 4; ++jn)
        acc[i][jn] = __builtin_amdgcn_mfma_f32_16x16x32_bf16(av[i], bv[jn], acc[i][jn], 0, 0, 0);
  }

  if (y < 2) {
    const float qsc = (y == 0) ? 0.14433756729740643f : 1.0f;  // 48^-0.5 folded into Q
    u16* ob = (y == 0) ? Qo : Ko;
#pragma unroll
    for (int i = 0; i < 4; ++i) {
      const int c0 = mbase + wr * 64 + i * 16 + lg * 4;
      const int hh = c0 / 48;
      const int d0 = c0 - hh * 48;
#pragma unroll
      for (int jn = 0; jn < 4; ++jn) {
        const int bn = nbase + wc * 64 + jn * 16 + lc;
        const int bb = bn / 576;
        const int nn = bn - bb * 576;
        ushort4 o;
        o.x = f2bf(acc[i][jn][0] * qsc); o.y = f2bf(acc[i][jn][1] * qsc);
        o.z = f2bf(acc[i][jn][2] * qsc); o.w = f2bf(acc[i][jn][3] * qsc);
        *(ushort4*)&ob[(((size_t)bb * 16 + hh) * 576 + nn) * 64 + d0] = o;
      }
    }
  } else {
#pragma unroll
    for (int i = 0; i < 4; ++i) {
      const int c0 = mbase + wr * 64 + i * 16 + lg * 4;
      const int hh = c0 / 48;
      const int d0 = c0 - hh * 48;
#pragma unroll
      for (int jn = 0; jn < 4; ++jn) {
        const int bn = nbase + wc * 64 + jn * 16 + lc;
        const int bb = bn / 576;
        const int nn = bn - bb * 576;
#pragma unroll
        for (int j = 0; j < 4; ++j)
          Vo[(((size_t)bb * 16 + hh) * 48 + d0 + j) * 576 + nn] = f2bf(acc[i][jn][j]);
      }
    }
  }
}

// ---------------- pos-attention GEMM: Og[b,h,q,d] = sum_m V[b,m,d] * posg[h,q,m] ----------------
// 1D grid 240 = 8 XCD x (2 heads x 15 tiles): same-h blocks share posg panel in one L2.
__global__ __launch_bounds__(256) void pos_gemm(const u16* __restrict__ VT,
                                                const u16* __restrict__ posg,
                                                u16* __restrict__ O) {
  __shared__ u16 sA[128][40];
  __shared__ u16 sB[128][40];

  const int id = blockIdx.x;
  const int xcd = id & 7;
  const int local = id >> 3;        // 0..29
  const int h = xcd * 2 + local / 15;
  const int r = local % 15;
  const int mt = r / 5, nt = r % 5;

  const int mbase = mt * 128, nbase = nt * 128;
  const int tid = threadIdx.x;
  const int w = tid >> 6, lane = tid & 63;
  const int wr = w >> 1, wc = w & 1;
  const int lg = lane >> 4, lc = lane & 15;
  const int rS = tid >> 2;
  const int cS = (tid & 3) * 8;

  const int mA0 = mbase + rS, mA1 = mA0 + 64;
  const u16* gA0 = VT + ((size_t)((mA0 / 48) * 16 + h) * 48 + (mA0 % 48)) * 576 + cS;
  const u16* gA1 = VT + ((size_t)((mA1 / 48) * 16 + h) * 48 + (mA1 % 48)) * 576 + cS;
  const u16* gB0 = posg + (size_t)(h * 576 + nbase + rS) * 576 + cS;
  const u16* gB1 = gB0 + (size_t)64 * 576;

  const f32x4 vzero = {0.f, 0.f, 0.f, 0.f};
  f32x4 acc[4][4];
#pragma unroll
  for (int i = 0; i < 4; ++i)
#pragma unroll
    for (int j = 0; j < 4; ++j) acc[i][j] = vzero;

  for (int kt = 0; kt < 18; ++kt) {
    const int kb = kt * 32;
    const bf16x8 a0 = *(const bf16x8*)(gA0 + kb);
    const bf16x8 a1 = *(const bf16x8*)(gA1 + kb);
    const bf16x8 b0 = *(const bf16x8*)(gB0 + kb);
    const bf16x8 b1 = *(const bf16x8*)(gB1 + kb);
    __syncthreads();
    *(bf16x8*)&sA[rS][cS] = a0;
    *(bf16x8*)&sA[rS + 64][cS] = a1;
    *(bf16x8*)&sB[rS][cS] = b0;
    *(bf16x8*)&sB[rS + 64][cS] = b1;
    __syncthreads();
    bf16x8 av[4], bv[4];
#pragma unroll
    for (int i = 0; i < 4; ++i) av[i] = *(const bf16x8*)&sA[wr * 64 + i * 16 + lc][lg * 8];
#pragma unroll
    for (int jn = 0; jn < 4; ++jn) bv[jn] = *(const bf16x8*)&sB[wc * 64 + jn * 16 + lc][lg * 8];
#pragma unroll
    for (int i = 0; i < 4; ++i)
#pragma unroll
      for (int jn = 0; jn < 4; ++jn)
        acc[i][jn] = __builtin_amdgcn_mfma_f32_16x16x32_bf16(av[i], bv[jn], acc[i][jn], 0, 0, 0);
  }

#pragma unroll
  for (int i = 0; i < 4; ++i) {
    const int c0 = mbase + wr * 64 + i * 16 + lg * 4;  // (b,d): 4 consecutive d in one head
    const int bb = c0 / 48;
    const int d0 = c0 - bb * 48;
#pragma unroll
    for (int jn = 0; jn < 4; ++jn) {
      const int q = nbase + wc * 64 + jn * 16 + lc;
      if (q < 576) {
        ushort4 o;
        o.x = f2bf(acc[i][jn][0]); o.y = f2bf(acc[i][jn][1]);
        o.z = f2bf(acc[i][jn][2]); o.w = f2bf(acc[i][jn][3]);
        *(ushort4*)&O[((size_t)(bb * 576 + q)) * 768 + h * 48 + d0] = o;
      }
    }
  }
}

// ---------------- fused patch attention (pos part pre-added in Ow) ----------------
// 1D grid 2304 = 8 XCD x (16 h x 18 qt): XCD x owns batch b=x entirely; per-XCD L2
// working set Q_b+K_b+V_b ~3.3MB < 4MB, so K/V re-reads across qt hit L2 not L3.
__global__ __launch_bounds__(256) void attn_fused(
    const u16* __restrict__ Q, const u16* __restrict__ K, const u16* __restrict__ VT,
    const float* __restrict__ gating, u16* __restrict__ O) {
  const int id = blockIdx.x;
  const int b = id & 7;             // XCD-aligned (round-robin dispatch)
  const int local = id >> 3;        // 0..287
  const int h = local / 18;
  const int qt = local % 18;
  const int tid = threadIdx.x;
  const int w = tid >> 6, lane = tid & 63;
  const int qh = w >> 1, ks = w & 1;
  const int lg = lane >> 4, lc = lane & 15;
  const int bh = b * 16 + h;

  const u16* Qh = Q + (size_t)bh * 576 * 64;
  const u16* Kh = K + (size_t)bh * 576 * 64;
  const u16* Vh = VT + (size_t)bh * 48 * 576;

  __shared__ u16 pls[4][2][16][40];   // per-wave patch-P repack, parity double-buffered
  __shared__ float red[2][64][17];    // split-k: 12 acc + 4 lsum

  const bf16x8 zer = {0, 0, 0, 0, 0, 0, 0, 0};
  const int qbase = qt * 32 + qh * 16;
  const bf16x8 aq0 = *(const bf16x8*)&Qh[(qbase + lc) * 64 + lg * 8];
  bf16x8 aq1 = zer;  // d 48..63 pad: zero in-register (both operands) instead of memset
  if (lg < 2) aq1 = *(const bf16x8*)&Qh[(qbase + lc) * 64 + lg * 8 + 32];

  const int kbase = ks * 288;

  bf16x8 kb[2][2][2];  // [buf][t][dhalf]
#pragma unroll
  for (int t = 0; t < 2; ++t) {
    kb[0][t][0] = *(const bf16x8*)&Kh[(kbase + t * 16 + lc) * 64 + lg * 8];
    kb[0][t][1] = zer;
    if (lg < 2) kb[0][t][1] = *(const bf16x8*)&Kh[(kbase + t * 16 + lc) * 64 + lg * 8 + 32];
  }

  const f32x4 vzero = {0.f, 0.f, 0.f, 0.f};
  f32x4 accP0 = vzero, accP1 = vzero, accP2 = vzero;
  float lsum[4] = {0.f, 0.f, 0.f, 0.f};
  bf16x8 paP = zer, vp0 = zer, vp1 = zer, vp2 = zer;

#pragma unroll
  for (int kc = 0; kc < 9; ++kc) {
    const int cur = kc & 1;
    const int k0 = kbase + kc * 32;
    if (kc < 8) {  // prefetch next K chunk
      const int k1 = k0 + 32;
#pragma unroll
      for (int t = 0; t < 2; ++t) {
        kb[cur ^ 1][t][0] = *(const bf16x8*)&Kh[(k1 + t * 16 + lc) * 64 + lg * 8];
        kb[cur ^ 1][t][1] = zer;
        if (lg < 2) kb[cur ^ 1][t][1] = *(const bf16x8*)&Kh[(k1 + t * 16 + lc) * 64 + lg * 8 + 32];
      }
    }
    // V for this chunk (consumed NEXT iteration -> full chunk of latency slack)
    const bf16x8 vb0 = *(const bf16x8*)&Vh[lc * 576 + k0 + lg * 8];
    const bf16x8 vb1 = *(const bf16x8*)&Vh[(16 + lc) * 576 + k0 + lg * 8];
    const bf16x8 vb2 = *(const bf16x8*)&Vh[(32 + lc) * 576 + k0 + lg * 8];

    f32x4 s0 = vzero, s1 = vzero;
    s0 = __builtin_amdgcn_mfma_f32_16x16x32_bf16(aq0, kb[cur][0][0], s0, 0, 0, 0);
    s0 = __builtin_amdgcn_mfma_f32_16x16x32_bf16(aq1, kb[cur][0][1], s0, 0, 0, 0);
    s1 = __builtin_amdgcn_mfma_f32_16x16x32_bf16(aq0, kb[cur][1][0], s1, 0, 0, 0);
    s1 = __builtin_amdgcn_mfma_f32_16x16x32_bf16(aq1, kb[cur][1][1], s1, 0, 0, 0);

    if (kc > 0) {  // PV of previous chunk: fills MFMA pipe while s0/s1 settle
      accP0 = __builtin_amdgcn_mfma_f32_16x16x32_bf16(paP, vp0, accP0, 0, 0, 0);
      accP1 = __builtin_amdgcn_mfma_f32_16x16x32_bf16(paP, vp1, accP1, 0, 0, 0);
      accP2 = __builtin_amdgcn_mfma_f32_16x16x32_bf16(paP, vp2, accP2, 0, 0, 0);
    }

#pragma unroll
    for (int j = 0; j < 4; ++j) {  // D row = lg*4+j, cols t*16+lc
      const float p0 = __expf(s0[j]);
      const float p1 = __expf(s1[j]);
      lsum[j] += p0 + p1;
      pls[w][cur][lg * 4 + j][lc] = f2bf(p0);
      pls[w][cur][lg * 4 + j][16 + lc] = f2bf(p1);
    }
    asm volatile("s_waitcnt lgkmcnt(0)" ::: "memory");  // wave-private LDS write->read
    paP = *(const bf16x8*)&pls[w][cur][lc][lg * 8];
    vp0 = vb0; vp1 = vb1; vp2 = vb2;
  }
  accP0 = __builtin_amdgcn_mfma_f32_16x16x32_bf16(paP, vp0, accP0, 0, 0, 0);
  accP1 = __builtin_amdgcn_mfma_f32_16x16x32_bf16(paP, vp1, accP1, 0, 0, 0);
  accP2 = __builtin_amdgcn_mfma_f32_16x16x32_bf16(paP, vp2, accP2, 0, 0, 0);

  float lred[4];
#pragma unroll
  for (int j = 0; j < 4; ++j) {
    float sv = lsum[j];
    sv += __shfl_xor(sv, 1, 64);
    sv += __shfl_xor(sv, 2, 64);
    sv += __shfl_xor(sv, 4, 64);
    sv += __shfl_xor(sv, 8, 64);
    lred[j] = sv;
  }

  if (ks == 1) {
#pragma unroll
    for (int j = 0; j < 4; ++j) {
      red[qh][lane][0 + j] = accP0[j];
      red[qh][lane][4 + j] = accP1[j];
      red[qh][lane][8 + j] = accP2[j];
      red[qh][lane][12 + j] = lred[j];
    }
  }
  __syncthreads();
  if (ks == 0) {
    const float g = 1.f / (1.f + __expf(-gating[h]));
    const float omg = 1.f - g;
    float linv[4];
#pragma unroll
    for (int j = 0; j < 4; ++j) linv[j] = omg / (lred[j] + red[qh][lane][12 + j]);
#pragma unroll
    for (int dt = 0; dt < 3; ++dt) {
#pragma unroll
      for (int j = 0; j < 4; ++j) {
        const float p = (dt == 0 ? accP0[j] : dt == 1 ? accP1[j] : accP2[j]) +
                        red[qh][lane][dt * 4 + j];
        const int qg = qbase + lg * 4 + j;
        const size_t idx = ((size_t)(b * 576 + qg)) * 768 + h * 48 + dt * 16 + lc;
        const float val = p * linv[j] + bf2f(O[idx]);  // add pre-computed g*O_pos
        O[idx] = f2bf(val);
      }
    }
  }
}

// ---------------- output projection: out = O @ Wproj^T + b ----------------
__global__ __launch_bounds__(256) void gemm_proj(const u16* __restrict__ A,
                                                 const u16* __restrict__ B,
                                                 float* __restrict__ of,
                                                 const float* __restrict__ bias) {
  __shared__ u16 sA[128][40];
  __shared__ u16 sB[128][40];

  const int mt = blockIdx.x / 36, nt = blockIdx.x % 36;
  const int mbase = mt * 128, nbase = nt * 128;
  const int tid = threadIdx.x;
  const int w = tid >> 6, lane = tid & 63;
  const int wr = w >> 1, wc = w & 1;
  const int lg = lane >> 4, lc = lane & 15;
  const int rS = tid >> 2;
  const int cS = (tid & 3) * 8;

  const u16* gA0 = A + (size_t)(mbase + rS) * 768 + cS;
  const u16* gA1 = gA0 + (size_t)64 * 768;
  const u16* gB0 = B + (size_t)(nbase + rS) * 768 + cS;
  const u16* gB1 = gB0 + (size_t)64 * 768;

  const f32x4 vzero = {0.f, 0.f, 0.f, 0.f};
  f32x4 acc[4][4];
#pragma unroll
  for (int i = 0; i < 4; ++i)
#pragma unroll
    for (int j = 0; j < 4; ++j) acc[i][j] = vzero;

  for (int kt = 0; kt < 24; ++kt) {
    const int kb = kt * 32;
    const bf16x8 a0 = *(const bf16x8*)(gA0 + kb);
    const bf16x8 a1 = *(const bf16x8*)(gA1 + kb);
    const bf16x8 b0 = *(const bf16x8*)(gB0 + kb);
    const bf16x8 b1 = *(const bf16x8*)(gB1 + kb);
    __syncthreads();
    *(bf16x8*)&sA[rS][cS] = a0;
    *(bf16x8*)&sA[rS + 64][cS] = a1;
    *(bf16x8*)&sB[rS][cS] = b0;
    *(bf16x8*)&sB[rS + 64][cS] = b1;
    __syncthreads();
    bf16x8 av[4], bv[4];
#pragma unroll
    for (int i = 0; i < 4; ++i) av[i] = *(const bf16x8*)&sA[wr * 64 + i * 16 + lc][lg * 8];
#pragma unroll
    for (int jn = 0; jn < 4; ++jn) bv[jn] = *(const bf16x8*)&sB[wc * 64 + jn * 16 + lc][lg * 8];
#pragma unroll
    for (int i = 0; i < 4; ++i)
#pragma unroll
      for (int jn = 0; jn < 4; ++jn)
        acc[i][jn] = __builtin_amdgcn_mfma_f32_16x16x32_bf16(av[i], bv[jn], acc[i][jn], 0, 0, 0);
  }

#pragma unroll
  for (int i = 0; i < 4; ++i) {
    const int c0 = mbase + wr * 64 + i * 16 + lg * 4;
    const float4 b4 = *(const float4*)&bias[c0];
#pragma unroll
    for (int jn = 0; jn < 4; ++jn) {
      const int bn = nbase + wc * 64 + jn * 16 + lc;
      float4 o;
      o.x = acc[i][jn][0] + b4.x; o.y = acc[i][jn][1] + b4.y;
      o.z = acc[i][jn][2] + b4.z; o.w = acc[i][jn][3] + b4.w;
      *(float4*)&of[(size_t)bn * 768 + c0] = o;
    }
  }
}

// ---------------- launch ----------------
extern "C" void kernel_launch(void* const* d_in, const int* in_sizes, int n_in,
                              void* d_out, int out_size, void* d_ws, size_t ws_size,
                              hipStream_t stream) {
  const float* x      = (const float*)d_in[0];
  const float* Wq     = (const float*)d_in[1];
  const float* Wk     = (const float*)d_in[2];
  const float* Wv     = (const float*)d_in[3];
  const float* Wp     = (const float*)d_in[4];
  const float* bproj  = (const float*)d_in[5];
  const float* Wpos   = (const float*)d_in[6];
  const float* bpos   = (const float*)d_in[7];
  const float* gating = (const float*)d_in[8];
  float* out = (float*)d_out;

  char* ws = (char*)d_ws;
  u16* xb   = (u16*)(ws + 0);
  u16* wqb  = (u16*)(ws + 7077888);
  u16* wkb  = (u16*)(ws + 8257536);
  u16* wvb  = (u16*)(ws + 9437184);
  u16* wpb  = (u16*)(ws + 10616832);
  u16* Qw   = (u16*)(ws + 11796480);
  u16* Kw   = (u16*)(ws + 21233664);
  u16* VTw  = (u16*)(ws + 30670848);
  u16* Ow   = (u16*)(ws + 37748736);
  u16* posg = (u16*)(ws + 0);  // overlays xb..wvb (dead after gemm_qkv); ends exactly at wpb

  cvt_all<<<dim3(5760), dim3(256), 0, stream>>>(x, Wq, Wk, Wv, Wp, xb);
  gemm_qkv<<<dim3(216, 3), dim3(256), 0, stream>>>(wqb, wkb, wvb, xb, Qw, Kw, VTw);
  pos_soft<<<dim3(2304), dim3(256), 0, stream>>>(Wpos, bpos, gating, posg);
  pos_gemm<<<dim3(240), dim3(256), 0, stream>>>(VTw, posg, Ow);
  attn_fused<<<dim3(2304), dim3(256), 0, stream>>>(Qw, Kw, VTw, gating, Ow);
  gemm_proj<<<dim3(216), dim3(256), 0, stream>>>(wpb, Ow, out, bproj);
}

// Round 5
// 146.313 us; speedup vs baseline: 1.1666x; 1.0853x over previous
//
#include <hip/hip_runtime.h>
#include <hip/hip_bf16.h>
#include <cstdint>

// ConViT GPSA fused pipeline, bf16 MFMA throughout.
// ws (~44.9 MB): xb(7.08M) wqb/wkb/wvb/wpb(1.18M ea) Q(9.44M) K(9.44M) VT(7.08M) O(7.08M)
// posg(10.6M) overlays [xb..wvb] after gemm_qkv consumes them (wpb at 10,616,832 survives).

typedef unsigned short u16;
typedef __attribute__((ext_vector_type(8))) short bf16x8;
typedef __attribute__((ext_vector_type(4))) float f32x4;

__device__ __forceinline__ u16 f2bf(float f) {
  union { float f; uint32_t u; } v; v.f = f;
  uint32_t r = v.u + 0x7FFFu + ((v.u >> 16) & 1u);  // RNE (no NaN in this workload)
  return (u16)(r >> 16);
}
__device__ __forceinline__ float bf2f(u16 u) {
  union { uint32_t u; float f; } v; v.u = ((uint32_t)u) << 16;
  return v.f;
}

// async global->LDS, 16B per lane; LDS dest is wave-uniform base + lane*16 (linear!)
__device__ __forceinline__ void gl_lds16(const u16* g, u16* l) {
  __builtin_amdgcn_global_load_lds(
      (const __attribute__((address_space(1))) void*)g,
      (__attribute__((address_space(3))) void*)l, 16, 0, 0);
}

// ---------------- f32 -> bf16: x + all 4 weights in one dispatch ----------------
__global__ __launch_bounds__(256) void cvt_all(const float* __restrict__ x,
                                               const float* __restrict__ Wq,
                                               const float* __restrict__ Wk,
                                               const float* __restrict__ Wv,
                                               const float* __restrict__ Wp,
                                               u16* __restrict__ dst) {
  const int i = blockIdx.x * 256 + threadIdx.x;  // 1,474,560 float4 items exactly
  const float* s;
  if (i < 884736) {
    s = x + (size_t)i * 4;
  } else {
    const int j = i - 884736;
    if (j < 147456) s = Wq + (size_t)j * 4;
    else if (j < 294912) s = Wk + (size_t)(j - 147456) * 4;
    else if (j < 442368) s = Wv + (size_t)(j - 294912) * 4;
    else s = Wp + (size_t)(j - 442368) * 4;
  }
  const float4 v = *(const float4*)s;
  ushort4 o;
  o.x = f2bf(v.x); o.y = f2bf(v.y); o.z = f2bf(v.z); o.w = f2bf(v.w);
  ((ushort4*)dst)[i] = o;
}

// ---------------- g-scaled positional softmax, materialized ----------------
__global__ __launch_bounds__(256) void pos_soft(const float* __restrict__ Wpos,
                                                const float* __restrict__ bpos,
                                                const float* __restrict__ gating,
                                                u16* __restrict__ posg) {
  const int w = threadIdx.x >> 6, lane = threadIdx.x & 63;
  const int row = blockIdx.x * 4 + w;            // 0..9215  (h*576+n)
  const int h = row / 576, n = row - h * 576;
  const float w0 = Wpos[h * 3 + 0], w1 = Wpos[h * 3 + 1], w2 = Wpos[h * 3 + 2], bp = bpos[h];
  const float g = 1.f / (1.f + __expf(-gating[h]));
  const int qr = n / 24, qc = n - qr * 24;
  float vals[9], evals[9];
  float mx = -1e30f;
#pragma unroll
  for (int i = 0; i < 9; ++i) {
    const int m = i * 64 + lane;
    const int kr = m / 24, kc = m - kr * 24;
    const float dx = (float)(kc - qc), dy = (float)(kr - qr);
    const float p = w0 * dx + w1 * dy + w2 * (dx * dx + dy * dy) + bp;
    vals[i] = p;
    mx = fmaxf(mx, p);
  }
#pragma unroll
  for (int off = 1; off < 64; off <<= 1) mx = fmaxf(mx, __shfl_xor(mx, off, 64));
  float s = 0.f;
#pragma unroll
  for (int i = 0; i < 9; ++i) { evals[i] = __expf(vals[i] - mx); s += evals[i]; }
#pragma unroll
  for (int off = 1; off < 64; off <<= 1) s += __shfl_xor(s, off, 64);
  const float gi = g / s;
  u16* out = posg + (size_t)row * 576;
#pragma unroll
  for (int i = 0; i < 9; ++i) out[i * 64 + lane] = f2bf(evals[i] * gi);
}

// ---------------- unified QKV projection (C = W @ x^T per mode), K = 768 ----------------
__global__ __launch_bounds__(256) void gemm_qkv(
    const u16* __restrict__ wq, const u16* __restrict__ wk, const u16* __restrict__ wv,
    const u16* __restrict__ xb, u16* __restrict__ Qo, u16* __restrict__ Ko,
    u16* __restrict__ Vo) {
  __shared__ u16 sA[128 * 32];  // linear, unpadded (global_load_lds dest)
  __shared__ u16 sB[128 * 32];

  const int y = blockIdx.y;
  const u16* A = y == 0 ? wq : y == 1 ? wk : wv;

  const int mt = blockIdx.x / 36, nt = blockIdx.x % 36;
  const int mbase = mt * 128, nbase = nt * 128;
  const int tid = threadIdx.x;
  const int w = tid >> 6, lane = tid & 63;
  const int wr = w >> 1, wc = w & 1;
  const int lg = lane >> 4, lc = lane & 15;
  const int lrow = lane >> 2;          // staging row within 16-row band
  const int lcol = (lane & 3) * 8;     // staging col (elems)

  const u16* srcA0 = A + (size_t)(mbase + w * 16 + lrow) * 768 + lcol;
  const u16* srcA1 = srcA0 + (size_t)64 * 768;
  const u16* srcB0 = xb + (size_t)(nbase + w * 16 + lrow) * 768 + lcol;
  const u16* srcB1 = srcB0 + (size_t)64 * 768;
  u16* dA0 = sA + w * 512;        // 16 rows * 32 elems per wave
  u16* dA1 = sA + 2048 + w * 512;
  u16* dB0 = sB + w * 512;
  u16* dB1 = sB + 2048 + w * 512;

  const f32x4 vzero = {0.f, 0.f, 0.f, 0.f};
  f32x4 acc[4][4];
#pragma unroll
  for (int i = 0; i < 4; ++i)
#pragma unroll
    for (int j = 0; j < 4; ++j) acc[i][j] = vzero;

  for (int kt = 0; kt < 24; ++kt) {
    const int kb = kt * 32;
    __syncthreads();  // previous iter's frag reads done before overwrite
    gl_lds16(srcA0 + kb, dA0);
    gl_lds16(srcA1 + kb, dA1);
    gl_lds16(srcB0 + kb, dB0);
    gl_lds16(srcB1 + kb, dB1);
    __syncthreads();  // drains vmcnt (loads landed in LDS)
    bf16x8 av[4], bv[4];
#pragma unroll
    for (int i = 0; i < 4; ++i) av[i] = *(const bf16x8*)&sA[(wr * 64 + i * 16 + lc) * 32 + lg * 8];
#pragma unroll
    for (int jn = 0; jn < 4; ++jn) bv[jn] = *(const bf16x8*)&sB[(wc * 64 + jn * 16 + lc) * 32 + lg * 8];
#pragma unroll
    for (int i = 0; i < 4; ++i)
#pragma unroll
      for (int jn = 0; jn < 4; ++jn)
        acc[i][jn] = __builtin_amdgcn_mfma_f32_16x16x32_bf16(av[i], bv[jn], acc[i][jn], 0, 0, 0);
  }

  if (y < 2) {
    const float qsc = (y == 0) ? 0.14433756729740643f : 1.0f;  // 48^-0.5 folded into Q
    u16* ob = (y == 0) ? Qo : Ko;
#pragma unroll
    for (int i = 0; i < 4; ++i) {
      const int c0 = mbase + wr * 64 + i * 16 + lg * 4;
      const int hh = c0 / 48;
      const int d0 = c0 - hh * 48;
#pragma unroll
      for (int jn = 0; jn < 4; ++jn) {
        const int bn = nbase + wc * 64 + jn * 16 + lc;
        const int bb = bn / 576;
        const int nn = bn - bb * 576;
        ushort4 o;
        o.x = f2bf(acc[i][jn][0] * qsc); o.y = f2bf(acc[i][jn][1] * qsc);
        o.z = f2bf(acc[i][jn][2] * qsc); o.w = f2bf(acc[i][jn][3] * qsc);
        *(ushort4*)&ob[(((size_t)bb * 16 + hh) * 576 + nn) * 64 + d0] = o;
      }
    }
  } else {
#pragma unroll
    for (int i = 0; i < 4; ++i) {
      const int c0 = mbase + wr * 64 + i * 16 + lg * 4;
      const int hh = c0 / 48;
      const int d0 = c0 - hh * 48;
#pragma unroll
      for (int jn = 0; jn < 4; ++jn) {
        const int bn = nbase + wc * 64 + jn * 16 + lc;
        const int bb = bn / 576;
        const int nn = bn - bb * 576;
#pragma unroll
        for (int j = 0; j < 4; ++j)
          Vo[(((size_t)bb * 16 + hh) * 48 + d0 + j) * 576 + nn] = f2bf(acc[i][jn][j]);
      }
    }
  }
}

// ---------------- pos-attention GEMM: Og[b,h,q,d] = sum_m V[b,m,d] * posg[h,q,m] ----------------
__global__ __launch_bounds__(256) void pos_gemm(const u16* __restrict__ VT,
                                                const u16* __restrict__ posg,
                                                u16* __restrict__ O) {
  __shared__ u16 sA[128 * 32];
  __shared__ u16 sB[128 * 32];

  const int id = blockIdx.x;
  const int xcd = id & 7;
  const int local = id >> 3;        // 0..29
  const int h = xcd * 2 + local / 15;
  const int r = local % 15;
  const int mt = r / 5, nt = r % 5;

  const int mbase = mt * 128, nbase = nt * 128;
  const int tid = threadIdx.x;
  const int w = tid >> 6, lane = tid & 63;
  const int wr = w >> 1, wc = w & 1;
  const int lg = lane >> 4, lc = lane & 15;
  const int lrow = lane >> 2;
  const int lcol = (lane & 3) * 8;

  const int mA0 = mbase + w * 16 + lrow, mA1 = mA0 + 64;
  const u16* srcA0 = VT + ((size_t)((mA0 / 48) * 16 + h) * 48 + (mA0 % 48)) * 576 + lcol;
  const u16* srcA1 = VT + ((size_t)((mA1 / 48) * 16 + h) * 48 + (mA1 % 48)) * 576 + lcol;
  const u16* srcB0 = posg + (size_t)(h * 576 + nbase + w * 16 + lrow) * 576 + lcol;
  const u16* srcB1 = srcB0 + (size_t)64 * 576;
  u16* dA0 = sA + w * 512;
  u16* dA1 = sA + 2048 + w * 512;
  u16* dB0 = sB + w * 512;
  u16* dB1 = sB + 2048 + w * 512;

  const f32x4 vzero = {0.f, 0.f, 0.f, 0.f};
  f32x4 acc[4][4];
#pragma unroll
  for (int i = 0; i < 4; ++i)
#pragma unroll
    for (int j = 0; j < 4; ++j) acc[i][j] = vzero;

  for (int kt = 0; kt < 18; ++kt) {
    const int kb = kt * 32;
    __syncthreads();
    gl_lds16(srcA0 + kb, dA0);
    gl_lds16(srcA1 + kb, dA1);
    gl_lds16(srcB0 + kb, dB0);
    gl_lds16(srcB1 + kb, dB1);
    __syncthreads();
    bf16x8 av[4], bv[4];
#pragma unroll
    for (int i = 0; i < 4; ++i) av[i] = *(const bf16x8*)&sA[(wr * 64 + i * 16 + lc) * 32 + lg * 8];
#pragma unroll
    for (int jn = 0; jn < 4; ++jn) bv[jn] = *(const bf16x8*)&sB[(wc * 64 + jn * 16 + lc) * 32 + lg * 8];
#pragma unroll
    for (int i = 0; i < 4; ++i)
#pragma unroll
      for (int jn = 0; jn < 4; ++jn)
        acc[i][jn] = __builtin_amdgcn_mfma_f32_16x16x32_bf16(av[i], bv[jn], acc[i][jn], 0, 0, 0);
  }

#pragma unroll
  for (int i = 0; i < 4; ++i) {
    const int c0 = mbase + wr * 64 + i * 16 + lg * 4;  // (b,d): 4 consecutive d in one head
    const int bb = c0 / 48;
    const int d0 = c0 - bb * 48;
#pragma unroll
    for (int jn = 0; jn < 4; ++jn) {
      const int q = nbase + wc * 64 + jn * 16 + lc;
      if (q < 576) {
        ushort4 o;
        o.x = f2bf(acc[i][jn][0]); o.y = f2bf(acc[i][jn][1]);
        o.z = f2bf(acc[i][jn][2]); o.w = f2bf(acc[i][jn][3]);
        *(ushort4*)&O[((size_t)(bb * 576 + q)) * 768 + h * 48 + d0] = o;
      }
    }
  }
}

// ---------------- fused patch attention (pos part pre-added in Ow) ----------------
// Swapped QK^T: S^T = mfma(K, Q) -> lane (lg,lc) holds 8 keys of ONE query (lc).
// P^T B-fragment for PV (O^T = mfma(V^T, P^T)) built in-register: cvt_pk + 8 ds_bpermute
// within lane-groups {lc,16+lc,32+lc,48+lc} -> no LDS P-repack, no lgkmcnt(0) drain.
__global__ __launch_bounds__(256) void attn_fused(
    const u16* __restrict__ Q, const u16* __restrict__ K, const u16* __restrict__ VT,
    const float* __restrict__ gating, u16* __restrict__ O) {
  const int id = blockIdx.x;
  const int b = id & 7;             // XCD-aligned (round-robin dispatch)
  const int local = id >> 3;        // 0..287
  const int h = local / 18;
  const int qt = local % 18;
  const int tid = threadIdx.x;
  const int w = tid >> 6, lane = tid & 63;
  const int qh = w >> 1, ks = w & 1;
  const int lg = lane >> 4, lc = lane & 15;
  const int bh = b * 16 + h;

  const u16* Qh = Q + (size_t)bh * 576 * 64;
  const u16* Kh = K + (size_t)bh * 576 * 64;
  const u16* Vh = VT + (size_t)bh * 48 * 576;

  __shared__ float red[2][64][13];    // split-k: 12 acc + 1 lsum (13 stride: bank-free)

  const bf16x8 zer = {0, 0, 0, 0, 0, 0, 0, 0};
  const int qbase = qt * 32 + qh * 16;
  // Q as B-operand: B[k=d][q=lc]
  const bf16x8 aq0 = *(const bf16x8*)&Qh[(qbase + lc) * 64 + lg * 8];
  bf16x8 aq1 = zer;  // d 48..63 pad: zero in-register (both operands)
  if (lg < 2) aq1 = *(const bf16x8*)&Qh[(qbase + lc) * 64 + lg * 8 + 32];

  const int kbase = ks * 288;

  bf16x8 kb[2][2][2];  // [buf][t][dhalf]; A-operand: A[key-row=lc][k=d]
#pragma unroll
  for (int t = 0; t < 2; ++t) {
    kb[0][t][0] = *(const bf16x8*)&Kh[(kbase + t * 16 + lc) * 64 + lg * 8];
    kb[0][t][1] = zer;
    if (lg < 2) kb[0][t][1] = *(const bf16x8*)&Kh[(kbase + t * 16 + lc) * 64 + lg * 8 + 32];
  }

  const f32x4 vzero = {0.f, 0.f, 0.f, 0.f};
  f32x4 accP0 = vzero, accP1 = vzero, accP2 = vzero;
  float lsum = 0.f;
  bf16x8 pfrag = zer, vp0 = zer, vp1 = zer, vp2 = zer;

  const int bpA = (((lg & 1) * 32) + lc) * 4;  // byte addr of source lane (groups 0/2)
  const int bpB = bpA + 64;                    // +16 lanes (groups 1/3)
  const bool hiK = lg >= 2;                    // this lane's keys are the t=1 (s1) band

#pragma unroll
  for (int kc = 0; kc < 9; ++kc) {
    const int cur = kc & 1;
    const int k0 = kbase + kc * 32;
    if (kc < 8) {  // prefetch next K chunk
      const int k1 = k0 + 32;
#pragma unroll
      for (int t = 0; t < 2; ++t) {
        kb[cur ^ 1][t][0] = *(const bf16x8*)&Kh[(k1 + t * 16 + lc) * 64 + lg * 8];
        kb[cur ^ 1][t][1] = zer;
        if (lg < 2) kb[cur ^ 1][t][1] = *(const bf16x8*)&Kh[(k1 + t * 16 + lc) * 64 + lg * 8 + 32];
      }
    }
    // V^T A-fragments for this chunk (consumed NEXT iteration)
    const bf16x8 vb0 = *(const bf16x8*)&Vh[lc * 576 + k0 + lg * 8];
    const bf16x8 vb1 = *(const bf16x8*)&Vh[(16 + lc) * 576 + k0 + lg * 8];
    const bf16x8 vb2 = *(const bf16x8*)&Vh[(32 + lc) * 576 + k0 + lg * 8];

    // S^T[key][q=lc]: s0 -> keys k0+lg*4+j, s1 -> keys k0+16+lg*4+j
    f32x4 s0 = vzero, s1 = vzero;
    s0 = __builtin_amdgcn_mfma_f32_16x16x32_bf16(kb[cur][0][0], aq0, s0, 0, 0, 0);
    s0 = __builtin_amdgcn_mfma_f32_16x16x32_bf16(kb[cur][0][1], aq1, s0, 0, 0, 0);
    s1 = __builtin_amdgcn_mfma_f32_16x16x32_bf16(kb[cur][1][0], aq0, s1, 0, 0, 0);
    s1 = __builtin_amdgcn_mfma_f32_16x16x32_bf16(kb[cur][1][1], aq1, s1, 0, 0, 0);

    if (kc > 0) {  // PV of previous chunk (independent of s0/s1 -> fills pipe)
      accP0 = __builtin_amdgcn_mfma_f32_16x16x32_bf16(vp0, pfrag, accP0, 0, 0, 0);
      accP1 = __builtin_amdgcn_mfma_f32_16x16x32_bf16(vp1, pfrag, accP1, 0, 0, 0);
      accP2 = __builtin_amdgcn_mfma_f32_16x16x32_bf16(vp2, pfrag, accP2, 0, 0, 0);
    }

    const float p00 = __expf(s0[0]), p01 = __expf(s0[1]);
    const float p02 = __expf(s0[2]), p03 = __expf(s0[3]);
    const float p10 = __expf(s1[0]), p11 = __expf(s1[1]);
    const float p12 = __expf(s1[2]), p13 = __expf(s1[3]);
    lsum += ((p00 + p01) + (p02 + p03)) + ((p10 + p11) + (p12 + p13));

    uint32_t c0, c1, d0, d1;  // packed bf16 pairs: c = s0-band keys, d = s1-band keys
    asm("v_cvt_pk_bf16_f32 %0, %1, %2" : "=v"(c0) : "v"(p00), "v"(p01));
    asm("v_cvt_pk_bf16_f32 %0, %1, %2" : "=v"(c1) : "v"(p02), "v"(p03));
    asm("v_cvt_pk_bf16_f32 %0, %1, %2" : "=v"(d0) : "v"(p10), "v"(p11));
    asm("v_cvt_pk_bf16_f32 %0, %1, %2" : "=v"(d1) : "v"(p12), "v"(p13));

    // Redistribute: dest lane (lg,lc) needs keys lg*8..lg*8+7 of query lc.
    // sources: lanes (lg&1)*32+lc (w0,w1) and +16 (w2,w3); c-words if lg<2 else d-words.
    const int a_c0 = __builtin_amdgcn_ds_bpermute(bpA, (int)c0);
    const int a_c1 = __builtin_amdgcn_ds_bpermute(bpA, (int)c1);
    const int a_d0 = __builtin_amdgcn_ds_bpermute(bpA, (int)d0);
    const int a_d1 = __builtin_amdgcn_ds_bpermute(bpA, (int)d1);
    const int b_c0 = __builtin_amdgcn_ds_bpermute(bpB, (int)c0);
    const int b_c1 = __builtin_amdgcn_ds_bpermute(bpB, (int)c1);
    const int b_d0 = __builtin_amdgcn_ds_bpermute(bpB, (int)d0);
    const int b_d1 = __builtin_amdgcn_ds_bpermute(bpB, (int)d1);
    union { uint32_t u[4]; bf16x8 v; } pf;
    pf.u[0] = hiK ? a_d0 : a_c0;
    pf.u[1] = hiK ? a_d1 : a_c1;
    pf.u[2] = hiK ? b_d0 : b_c0;
    pf.u[3] = hiK ? b_d1 : b_c1;
    pfrag = pf.v;
    vp0 = vb0; vp1 = vb1; vp2 = vb2;
  }
  accP0 = __builtin_amdgcn_mfma_f32_16x16x32_bf16(vp0, pfrag, accP0, 0, 0, 0);
  accP1 = __builtin_amdgcn_mfma_f32_16x16x32_bf16(vp1, pfrag, accP1, 0, 0, 0);
  accP2 = __builtin_amdgcn_mfma_f32_16x16x32_bf16(vp2, pfrag, accP2, 0, 0, 0);

  // per-query (lc) row-sum for this k-half: reduce across the 4 lane-groups
  float ls = lsum;
  ls += __shfl_xor(ls, 16, 64);
  ls += __shfl_xor(ls, 32, 64);

  if (ks == 1) {
#pragma unroll
    for (int j = 0; j < 4; ++j) {
      red[qh][lane][0 + j] = accP0[j];
      red[qh][lane][4 + j] = accP1[j];
      red[qh][lane][8 + j] = accP2[j];
    }
    red[qh][lane][12] = ls;
  }
  __syncthreads();
  if (ks == 0) {
    const float g = 1.f / (1.f + __expf(-gating[h]));
    const float linv = (1.f - g) / (ls + red[qh][lane][12]);  // uniform per lane (query lc)
    const int row = b * 576 + qbase + lc;
#pragma unroll
    for (int dt = 0; dt < 3; ++dt) {
      const f32x4 a = dt == 0 ? accP0 : dt == 1 ? accP1 : accP2;
      const size_t idx = (size_t)row * 768 + h * 48 + dt * 16 + lg * 4;
      const ushort4 old4 = *(const ushort4*)&O[idx];
      ushort4 o;
      o.x = f2bf((a[0] + red[qh][lane][dt * 4 + 0]) * linv + bf2f(old4.x));
      o.y = f2bf((a[1] + red[qh][lane][dt * 4 + 1]) * linv + bf2f(old4.y));
      o.z = f2bf((a[2] + red[qh][lane][dt * 4 + 2]) * linv + bf2f(old4.z));
      o.w = f2bf((a[3] + red[qh][lane][dt * 4 + 3]) * linv + bf2f(old4.w));
      *(ushort4*)&O[idx] = o;
    }
  }
}

// ---------------- output projection: out = O @ Wproj^T + b ----------------
__global__ __launch_bounds__(256) void gemm_proj(const u16* __restrict__ A,
                                                 const u16* __restrict__ B,
                                                 float* __restrict__ of,
                                                 const float* __restrict__ bias) {
  __shared__ u16 sA[128 * 32];
  __shared__ u16 sB[128 * 32];

  const int mt = blockIdx.x / 36, nt = blockIdx.x % 36;
  const int mbase = mt * 128, nbase = nt * 128;
  const int tid = threadIdx.x;
  const int w = tid >> 6, lane = tid & 63;
  const int wr = w >> 1, wc = w & 1;
  const int lg = lane >> 4, lc = lane & 15;
  const int lrow = lane >> 2;
  const int lcol = (lane & 3) * 8;

  const u16* srcA0 = A + (size_t)(mbase + w * 16 + lrow) * 768 + lcol;
  const u16* srcA1 = srcA0 + (size_t)64 * 768;
  const u16* srcB0 = B + (size_t)(nbase + w * 16 + lrow) * 768 + lcol;
  const u16* srcB1 = srcB0 + (size_t)64 * 768;
  u16* dA0 = sA + w * 512;
  u16* dA1 = sA + 2048 + w * 512;
  u16* dB0 = sB + w * 512;
  u16* dB1 = sB + 2048 + w * 512;

  const f32x4 vzero = {0.f, 0.f, 0.f, 0.f};
  f32x4 acc[4][4];
#pragma unroll
  for (int i = 0; i < 4; ++i)
#pragma unroll
    for (int j = 0; j < 4; ++j) acc[i][j] = vzero;

  for (int kt = 0; kt < 24; ++kt) {
    const int kb = kt * 32;
    __syncthreads();
    gl_lds16(srcA0 + kb, dA0);
    gl_lds16(srcA1 + kb, dA1);
    gl_lds16(srcB0 + kb, dB0);
    gl_lds16(srcB1 + kb, dB1);
    __syncthreads();
    bf16x8 av[4], bv[4];
#pragma unroll
    for (int i = 0; i < 4; ++i) av[i] = *(const bf16x8*)&sA[(wr * 64 + i * 16 + lc) * 32 + lg * 8];
#pragma unroll
    for (int jn = 0; jn < 4; ++jn) bv[jn] = *(const bf16x8*)&sB[(wc * 64 + jn * 16 + lc) * 32 + lg * 8];
#pragma unroll
    for (int i = 0; i < 4; ++i)
#pragma unroll
      for (int jn = 0; jn < 4; ++jn)
        acc[i][jn] = __builtin_amdgcn_mfma_f32_16x16x32_bf16(av[i], bv[jn], acc[i][jn], 0, 0, 0);
  }

#pragma unroll
  for (int i = 0; i < 4; ++i) {
    const int c0 = mbase + wr * 64 + i * 16 + lg * 4;
    const float4 b4 = *(const float4*)&bias[c0];
#pragma unroll
    for (int jn = 0; jn < 4; ++jn) {
      const int bn = nbase + wc * 64 + jn * 16 + lc;
      float4 o;
      o.x = acc[i][jn][0] + b4.x; o.y = acc[i][jn][1] + b4.y;
      o.z = acc[i][jn][2] + b4.z; o.w = acc[i][jn][3] + b4.w;
      *(float4*)&of[(size_t)bn * 768 + c0] = o;
    }
  }
}

// ---------------- launch ----------------
extern "C" void kernel_launch(void* const* d_in, const int* in_sizes, int n_in,
                              void* d_out, int out_size, void* d_ws, size_t ws_size,
                              hipStream_t stream) {
  const float* x      = (const float*)d_in[0];
  const float* Wq     = (const float*)d_in[1];
  const float* Wk     = (const float*)d_in[2];
  const float* Wv     = (const float*)d_in[3];
  const float* Wp     = (const float*)d_in[4];
  const float* bproj  = (const float*)d_in[5];
  const float* Wpos   = (const float*)d_in[6];
  const float* bpos   = (const float*)d_in[7];
  const float* gating = (const float*)d_in[8];
  float* out = (float*)d_out;

  char* ws = (char*)d_ws;
  u16* xb   = (u16*)(ws + 0);
  u16* wqb  = (u16*)(ws + 7077888);
  u16* wkb  = (u16*)(ws + 8257536);
  u16* wvb  = (u16*)(ws + 9437184);
  u16* wpb  = (u16*)(ws + 10616832);
  u16* Qw   = (u16*)(ws + 11796480);
  u16* Kw   = (u16*)(ws + 21233664);
  u16* VTw  = (u16*)(ws + 30670848);
  u16* Ow   = (u16*)(ws + 37748736);
  u16* posg = (u16*)(ws + 0);  // overlays xb..wvb (dead after gemm_qkv); ends exactly at wpb

  cvt_all<<<dim3(5760), dim3(256), 0, stream>>>(x, Wq, Wk, Wv, Wp, xb);
  gemm_qkv<<<dim3(216, 3), dim3(256), 0, stream>>>(wqb, wkb, wvb, xb, Qw, Kw, VTw);
  pos_soft<<<dim3(2304), dim3(256), 0, stream>>>(Wpos, bpos, gating, posg);
  pos_gemm<<<dim3(240), dim3(256), 0, stream>>>(VTw, posg, Ow);
  attn_fused<<<dim3(2304), dim3(256), 0, stream>>>(Qw, Kw, VTw, gating, Ow);
  gemm_proj<<<dim3(216), dim3(256), 0, stream>>>(wpb, Ow, out, bproj);
}